// Round 3
// baseline (606.574 us; speedup 1.0000x reference)
//
#include <hip/hip_runtime.h>
#include <cstdint>
#include <cstddef>

// ---------------------------------------------------------------------------
// RegionSelectionAttention. Round 12: double-buffered single-barrier LDS
// K-loops for conv_down / convT / pw (write buf[cur] from regs; prefetch
// next chunk; one __syncthreads; MFMA buf[cur]). convT & pw retiled from
// 128x64 (110.6KB LDS, 1 block/CU) to 64x64 + dbuf (73.7KB, 2 blocks/CU).
// Attention kernels keep round-11 Q-in-registers form. Arithmetic unchanged
// (bit-identical outputs).
// ---------------------------------------------------------------------------

#define EPS_ 1e-5f

typedef short bf16x8_t __attribute__((ext_vector_type(8)));
typedef float f32x4_t __attribute__((ext_vector_type(4)));
#define MFMA16(a, b, c) __builtin_amdgcn_mfma_f32_16x16x32_bf16(a, b, c, 0, 0, 0)

__device__ __forceinline__ void cvt1(float f, unsigned short& h, unsigned short& l) {
  unsigned u = __float_as_uint(f);
  unsigned r = u + 0x7FFFu + ((u >> 16) & 1u);
  h = (unsigned short)(r >> 16);
  float lo = f - __uint_as_float(r & 0xFFFF0000u);
  l = (unsigned short)(__float_as_uint(lo) >> 16);
}
__device__ __forceinline__ unsigned cvtpack(float f) {
  unsigned short h, l;
  cvt1(f, h, l);
  return (unsigned)h | ((unsigned)l << 16);
}
__device__ __forceinline__ void cvt2(float f0, float f1, unsigned& hpack, unsigned& lpack) {
  unsigned u0 = __float_as_uint(f0), u1 = __float_as_uint(f1);
  unsigned r0 = u0 + 0x7FFFu + ((u0 >> 16) & 1u);
  unsigned r1 = u1 + 0x7FFFu + ((u1 >> 16) & 1u);
  hpack = (r0 >> 16) | (r1 & 0xFFFF0000u);
  float l0 = f0 - __uint_as_float(r0 & 0xFFFF0000u);
  float l1 = f1 - __uint_as_float(r1 & 0xFFFF0000u);
  lpack = (__float_as_uint(l0) >> 16) | (__float_as_uint(l1) & 0xFFFF0000u);
}
__device__ __forceinline__ unsigned pk_h(unsigned a, unsigned b) {
  return (a & 0xFFFFu) | (b << 16);
}
__device__ __forceinline__ unsigned pk_l(unsigned a, unsigned b) {
  return (a >> 16) | (b & 0xFFFF0000u);
}

// ---------------- pad x -> packed xphl[plane][66 rows x stride 68] ---------
__global__ __launch_bounds__(256) void k_pad_x(
    const float* __restrict__ x, unsigned* __restrict__ xphl) {
  const int plane = blockIdx.x;  // 2048
  const float* src = x + (size_t)plane * 4096;
  unsigned* dst = xphl + (size_t)plane * 4488;
  for (int e = threadIdx.x; e < 4356; e += 256) {
    int r = e / 66, cc = e - r * 66;
    float v = 0.f;
    if (r >= 1 && r <= 64 && cc >= 1 && cc <= 64) v = src[(r - 1) * 64 + (cc - 1)];
    dst[r * 68 + cc] = cvtpack(v);
  }
}

// ---------------- weight conversions ---------------------------------------
__global__ __launch_bounds__(256) void k_cvt_wdown(
    const float* __restrict__ w, unsigned short* __restrict__ wh,
    unsigned short* __restrict__ wl) {
  int e = blockIdx.x * 256 + threadIdx.x;  // 1,048,576: [oc][4096]
  cvt1(w[e], wh[e], wl[e]);
}

__global__ __launch_bounds__(256) void k_cvt_wqkv(
    const float* __restrict__ wq, unsigned short* __restrict__ wh,
    unsigned short* __restrict__ wl) {
  int e = blockIdx.x * 256 + threadIdx.x;  // 12288: [col][d]
  int col = e >> 6, d = e & 63;
  float f = wq[d * 192 + col];
  if (col < 64) f *= 0.125f;  // fold attn scale into q (pow2: exact)
  cvt1(f, wh[e], wl[e]);
}

__global__ __launch_bounds__(256) void k_cvt_wup(
    const float* __restrict__ w_up, unsigned short* __restrict__ wth,
    unsigned short* __restrict__ wtl) {
  int e = blockIdx.x * 256 + threadIdx.x;  // 2^20: [class][oc][kp=tap*256+ic]
  int kp = e & 1023, oc = (e >> 10) & 255, c = e >> 18;
  int tap = kp >> 8, ic = kp & 255;
  int tk = tap >> 1, txi = tap & 1;
  int ry = c >> 1, rx = c & 1;
  int ky = (1 - ry) + 2 * tk, kx = (1 - rx) + 2 * txi;
  cvt1(w_up[((size_t)(ic * 256 + oc) * 4 + ky) * 4 + kx], wth[e], wtl[e]);
}

__global__ __launch_bounds__(256) void k_cvt_wpw(
    const float* __restrict__ w, unsigned short* __restrict__ wh,
    unsigned short* __restrict__ wl) {
  int e = blockIdx.x * 256 + threadIdx.x;  // 65536 [oc][ic]
  cvt1(w[e], wh[e], wl[e]);
}

// ====================== MFMA cores =========================================
__device__ __forceinline__ void mfma_chunk(
    const unsigned short (*Ah)[72], const unsigned short (*Al)[72],
    const unsigned short (*Bh)[72], const unsigned short (*Bl)[72],
    f32x4_t (&acc)[4], int wm, int lane) {
  const int l16 = lane & 15, quad = lane >> 4;
#pragma unroll
  for (int ks = 0; ks < 2; ++ks) {
    int ko = ks * 32 + quad * 8;
    bf16x8_t ah = *(const bf16x8_t*)&Ah[wm + l16][ko];
    bf16x8_t al = *(const bf16x8_t*)&Al[wm + l16][ko];
#pragma unroll
    for (int nt = 0; nt < 4; ++nt) {
      bf16x8_t bh = *(const bf16x8_t*)&Bh[nt * 16 + l16][ko];
      bf16x8_t bl = *(const bf16x8_t*)&Bl[nt * 16 + l16][ko];
      acc[nt] = MFMA16(ah, bh, acc[nt]);
      acc[nt] = MFMA16(ah, bl, acc[nt]);
      acc[nt] = MFMA16(al, bh, acc[nt]);
    }
  }
}

// S-stage with the loop-invariant Q panel held in registers (B operand).
__device__ __forceinline__ void mfma_chunk_regB(
    const unsigned short (*Ah)[72], const unsigned short (*Al)[72],
    const bf16x8_t (&bh)[2][4], const bf16x8_t (&bl)[2][4],
    f32x4_t (&acc)[4], int wm, int lane) {
  const int l16 = lane & 15, quad = lane >> 4;
#pragma unroll
  for (int ks = 0; ks < 2; ++ks) {
    int ko = ks * 32 + quad * 8;
    bf16x8_t ah = *(const bf16x8_t*)&Ah[wm + l16][ko];
    bf16x8_t al = *(const bf16x8_t*)&Al[wm + l16][ko];
#pragma unroll
    for (int nt = 0; nt < 4; ++nt) {
      acc[nt] = MFMA16(ah, bh[ks][nt], acc[nt]);
      acc[nt] = MFMA16(ah, bl[ks][nt], acc[nt]);
      acc[nt] = MFMA16(al, bh[ks][nt], acc[nt]);
    }
  }
}

__device__ __forceinline__ void mfma_tile2x2(
    const unsigned short (*Ah)[72], const unsigned short (*Al)[72],
    const unsigned short (*Bh)[72], const unsigned short (*Bl)[72],
    f32x4_t (&acc)[2][2], int wm, int wn, int lane) {
  const int l16 = lane & 15, quad = lane >> 4;
#pragma unroll
  for (int ks = 0; ks < 2; ++ks) {
    int ko = ks * 32 + quad * 8;
    bf16x8_t ah[2], al[2];
#pragma unroll
    for (int mt = 0; mt < 2; ++mt) {
      ah[mt] = *(const bf16x8_t*)&Ah[wm + mt * 16 + l16][ko];
      al[mt] = *(const bf16x8_t*)&Al[wm + mt * 16 + l16][ko];
    }
#pragma unroll
    for (int nt = 0; nt < 2; ++nt) {
      bf16x8_t bh = *(const bf16x8_t*)&Bh[wn + nt * 16 + l16][ko];
      bf16x8_t bl = *(const bf16x8_t*)&Bl[wn + nt * 16 + l16][ko];
#pragma unroll
      for (int mt = 0; mt < 2; ++mt) {
        acc[mt][nt] = MFMA16(ah[mt], bh, acc[mt][nt]);
        acc[mt][nt] = MFMA16(ah[mt], bl, acc[mt][nt]);
        acc[mt][nt] = MFMA16(al[mt], bh, acc[mt][nt]);
      }
    }
  }
}

// ---------------- conv down k4 s2 p1, 64oc x 64pix, 2x2 waves, K=4096 ------
// Double-buffered LDS, one barrier per chunk.
__global__ __launch_bounds__(256) void k_conv_down_mfma(
    const unsigned* __restrict__ xphl, const unsigned short* __restrict__ wdh,
    const unsigned short* __restrict__ wdl, const float* __restrict__ bias,
    unsigned* __restrict__ xdhl) {
  __shared__ unsigned short Ah[2][64][72], Al[2][64][72];
  __shared__ unsigned short Bh[2][64][72], Bl[2][64][72];
  const int t = threadIdx.x;
  const int pix0 = blockIdx.x * 64, oc0 = blockIdx.y * 64;
  const int bimg = pix0 >> 10, pos = pix0 & 1023;
  const int pl = t & 63, icg = t >> 6;
  const int rem = (pix0 + pl) & 1023;
  const int oy = rem >> 5, ox = rem & 31;
  const unsigned* xb = xphl + ((size_t)bimg * 256 + icg) * 4488 + (oy * 2) * 68 + ox * 2;
  const int wave = t >> 6, lane = t & 63, l16 = lane & 15, quad = lane >> 4;
  const int wm = (wave & 1) * 32, wn = (wave >> 1) * 32;
  const int ar = t >> 2, ac = (t & 3) * 16;
  const unsigned short* wra = wdh + (size_t)(oc0 + ar) * 4096 + ac;
  const unsigned short* wrl = wdl + (size_t)(oc0 + ar) * 4096 + ac;
  f32x4_t acc[2][2] = {};
  bf16x8_t a0, a1, a2, a3;
  uint2 u01[4], u23[4];
  // prologue: chunk kb=0
  a0 = *(const bf16x8_t*)(wra);
  a1 = *(const bf16x8_t*)(wra + 8);
  a2 = *(const bf16x8_t*)(wrl);
  a3 = *(const bf16x8_t*)(wrl + 8);
#pragma unroll
  for (int r = 0; r < 4; ++r) {
    u01[r] = *(const uint2*)(xb + r * 68);
    u23[r] = *(const uint2*)(xb + r * 68 + 2);
  }
  int cur = 0;
  for (int kb = 0; kb < 4096; kb += 64) {
    unsigned hp[8], lp[8];
#pragma unroll
    for (int r = 0; r < 4; ++r) {
      hp[2 * r]     = pk_h(u01[r].x, u01[r].y);
      lp[2 * r]     = pk_l(u01[r].x, u01[r].y);
      hp[2 * r + 1] = pk_h(u23[r].x, u23[r].y);
      lp[2 * r + 1] = pk_l(u23[r].x, u23[r].y);
    }
    *(bf16x8_t*)&Ah[cur][ar][ac] = a0;
    *(bf16x8_t*)&Ah[cur][ar][ac + 8] = a1;
    *(bf16x8_t*)&Al[cur][ar][ac] = a2;
    *(bf16x8_t*)&Al[cur][ar][ac + 8] = a3;
    *(uint4*)&Bh[cur][pl][icg * 16] = make_uint4(hp[0], hp[1], hp[2], hp[3]);
    *(uint4*)&Bh[cur][pl][icg * 16 + 8] = make_uint4(hp[4], hp[5], hp[6], hp[7]);
    *(uint4*)&Bl[cur][pl][icg * 16] = make_uint4(lp[0], lp[1], lp[2], lp[3]);
    *(uint4*)&Bl[cur][pl][icg * 16 + 8] = make_uint4(lp[4], lp[5], lp[6], lp[7]);
    if (kb + 64 < 4096) {  // prefetch next chunk into registers
      xb += 4 * 4488;
      a0 = *(const bf16x8_t*)(wra + kb + 64);
      a1 = *(const bf16x8_t*)(wra + kb + 64 + 8);
      a2 = *(const bf16x8_t*)(wrl + kb + 64);
      a3 = *(const bf16x8_t*)(wrl + kb + 64 + 8);
#pragma unroll
      for (int r = 0; r < 4; ++r) {
        u01[r] = *(const uint2*)(xb + r * 68);
        u23[r] = *(const uint2*)(xb + r * 68 + 2);
      }
    }
    __syncthreads();  // buf[cur] writes visible; prior reads of buf[cur] done
    mfma_tile2x2(Ah[cur], Al[cur], Bh[cur], Bl[cur], acc, wm, wn, lane);
    cur ^= 1;
  }
#pragma unroll
  for (int mt = 0; mt < 2; ++mt)
#pragma unroll
    for (int r = 0; r < 4; ++r) {
      int oc = oc0 + wm + mt * 16 + quad * 4 + r;
      float bv = bias[oc];
#pragma unroll
      for (int nt = 0; nt < 2; ++nt)
        xdhl[((size_t)(bimg * 256 + oc)) * 1024 + pos + wn + nt * 16 + l16] =
            cvtpack(acc[mt][nt][r] + bv);
    }
}

// ---------------- qkv projection -------------------------------------------
template <int MODE>
__global__ __launch_bounds__(256) void k_qkv_mfma(
    const unsigned* __restrict__ srcp, const float* __restrict__ srcf,
    const unsigned short* __restrict__ wh, const unsigned short* __restrict__ wl,
    const float* __restrict__ bq, const int* __restrict__ topk,
    unsigned short* __restrict__ qh, unsigned short* __restrict__ ql,
    unsigned short* __restrict__ kh, unsigned short* __restrict__ kl,
    unsigned short* __restrict__ vth, unsigned short* __restrict__ vtl) {
  __shared__ unsigned short Ah[64][72], Al[64][72];
  const int t = threadIdx.x;
  const int tok0 = blockIdx.x * 64;
  const int pair = blockIdx.y;
  const int b = pair >> 2, h = pair & 3;
  const int tokl = t & 63, dg = t >> 6;
  unsigned hp[8], lp[8];
  if (MODE == 0) {
    const unsigned* base = srcp + ((size_t)(b * 256 + h * 64 + dg * 16)) * 1024 + tok0 + tokl;
    unsigned u[16];
#pragma unroll
    for (int j = 0; j < 16; ++j) u[j] = base[(size_t)j * 1024];
#pragma unroll
    for (int j = 0; j < 8; ++j) {
      hp[j] = pk_h(u[2 * j], u[2 * j + 1]);
      lp[j] = pk_l(u[2 * j], u[2 * j + 1]);
    }
  } else {
    int tok = tok0 + tokl;
    int pp = topk[pair * 256 + (tok >> 2)];
    int py = (tok >> 1) & 1, px = tok & 1;
    int ry = (pp >> 5) * 2 + py, rx = (pp & 31) * 2 + px;
    const float* base = srcf + ((size_t)(b * 256 + h * 64 + dg * 16)) * 4096 + ry * 64 + rx;
    float fv[16];
#pragma unroll
    for (int j = 0; j < 16; ++j) fv[j] = base[(size_t)j * 4096];
#pragma unroll
    for (int j = 0; j < 8; ++j) cvt2(fv[2 * j], fv[2 * j + 1], hp[j], lp[j]);
  }
  *(uint4*)&Ah[tokl][dg * 16] = make_uint4(hp[0], hp[1], hp[2], hp[3]);
  *(uint4*)&Ah[tokl][dg * 16 + 8] = make_uint4(hp[4], hp[5], hp[6], hp[7]);
  *(uint4*)&Al[tokl][dg * 16] = make_uint4(lp[0], lp[1], lp[2], lp[3]);
  *(uint4*)&Al[tokl][dg * 16 + 8] = make_uint4(lp[4], lp[5], lp[6], lp[7]);
  __syncthreads();
  const int wave = t >> 6, lane = t & 63, l16 = lane & 15, quad = lane >> 4;
  f32x4_t acc[4][3] = {};
#pragma unroll
  for (int ks = 0; ks < 2; ++ks) {
    int ko = ks * 32 + quad * 8;
    bf16x8_t bh0[3], bl0[3];
#pragma unroll
    for (int nt = 0; nt < 3; ++nt) {
      int col = wave * 48 + nt * 16 + l16;
      bh0[nt] = *(const bf16x8_t*)(wh + col * 64 + ko);
      bl0[nt] = *(const bf16x8_t*)(wl + col * 64 + ko);
    }
#pragma unroll
    for (int mt = 0; mt < 4; ++mt) {
      bf16x8_t ah = *(const bf16x8_t*)&Ah[mt * 16 + l16][ko];
      bf16x8_t al = *(const bf16x8_t*)&Al[mt * 16 + l16][ko];
#pragma unroll
      for (int nt = 0; nt < 3; ++nt) {
        acc[mt][nt] = MFMA16(ah, bh0[nt], acc[mt][nt]);
        acc[mt][nt] = MFMA16(ah, bl0[nt], acc[mt][nt]);
        acc[mt][nt] = MFMA16(al, bh0[nt], acc[mt][nt]);
      }
    }
  }
#pragma unroll
  for (int nt = 0; nt < 3; ++nt) {
    int col = wave * 48 + nt * 16 + l16;
    float bqv = bq[col];
    if (col < 64) bqv *= 0.125f;
#pragma unroll
    for (int mt = 0; mt < 4; ++mt) {
#pragma unroll
      for (int r = 0; r < 4; ++r) {
        int tok = tok0 + mt * 16 + quad * 4 + r;
        float val = acc[mt][nt][r] + bqv;
        unsigned short hh, ll;
        cvt1(val, hh, ll);
        if (col < 64) {
          size_t o = ((size_t)pair * 1024 + tok) * 64 + col;
          qh[o] = hh; ql[o] = ll;
        } else if (col < 128) {
          size_t o = ((size_t)pair * 1024 + tok) * 64 + (col - 64);
          kh[o] = hh; kl[o] = ll;
        } else {
          size_t o = ((size_t)pair * 64 + (col - 128)) * 1024 + tok;
          vth[o] = hh; vtl[o] = ll;
        }
      }
    }
  }
}

// ---------------- coarse fused attention (score path, bit-identical) -------
// Q panel in registers; K (pass1) / K+V (pass2) register-prefetched.
__global__ __launch_bounds__(256, 2) void k_attn_coarse(
    const unsigned short* __restrict__ qh, const unsigned short* __restrict__ ql,
    const unsigned short* __restrict__ kh, const unsigned short* __restrict__ kl,
    const unsigned short* __restrict__ vth, const unsigned short* __restrict__ vtl,
    float* __restrict__ score, unsigned* __restrict__ outc) {
  __shared__ __align__(16) unsigned short Kb[2][64][72];
  __shared__ __align__(16) unsigned short Vb[2][64][72];
  __shared__ __align__(16) unsigned short Pb[2][64][72];
  __shared__ float mlW[4][2][64];
  __shared__ float mC[64], lC[64];
  __shared__ float colsum[1024];
  const int t = threadIdx.x;
  const int q0 = blockIdx.x * 64;
  const int pair = blockIdx.y;
  const int wave = t >> 6, lane = t & 63;
  const int l16 = lane & 15, quad = lane >> 4;
  const int wm = wave * 16;
  const int sr = t >> 3, skc = (t & 7) * 8;

  const size_t qbase = ((size_t)pair * 1024 + q0) * 64;
  // Q fragments in registers: B-operand rows nt*16+l16, k-slice ks*32+quad*8
  bf16x8_t qh_r[2][4], ql_r[2][4];
#pragma unroll
  for (int ks = 0; ks < 2; ++ks)
#pragma unroll
    for (int nt = 0; nt < 4; ++nt) {
      int row = nt * 16 + l16, col = ks * 32 + quad * 8;
      qh_r[ks][nt] = *(const bf16x8_t*)(qh + qbase + (size_t)row * 64 + col);
      ql_r[ks][nt] = *(const bf16x8_t*)(ql + qbase + (size_t)row * 64 + col);
    }
#pragma unroll
  for (int i = 0; i < 4; ++i) colsum[t + i * 256] = 0.f;

  const size_t kmbase = (size_t)pair * 1024 * 64;
  const size_t vbase = (size_t)pair * 64 * 1024;

  // prologue prefetch: pass-1 chunk 0
  bf16x8_t pk0[2], pk1[2];
#pragma unroll
  for (int i = 0; i < 2; ++i) {
    int r = sr + i * 32;
    pk0[i] = *(const bf16x8_t*)(kh + kmbase + (size_t)r * 64 + skc);
    pk1[i] = *(const bf16x8_t*)(kl + kmbase + (size_t)r * 64 + skc);
  }

  // ---- pass 1: online (m,l), numerics identical ----
  float mrun[4] = {-1e30f, -1e30f, -1e30f, -1e30f};
  float lrun[4] = {0.f, 0.f, 0.f, 0.f};
  for (int kb = 0; kb < 1024; kb += 64) {
    __syncthreads();
#pragma unroll
    for (int i = 0; i < 2; ++i) {
      int r = sr + i * 32;
      *(bf16x8_t*)&Kb[0][r][skc] = pk0[i];
      *(bf16x8_t*)&Kb[1][r][skc] = pk1[i];
    }
    if (kb + 64 < 1024) {  // prefetch next chunk
#pragma unroll
      for (int i = 0; i < 2; ++i) {
        int r = sr + i * 32;
        pk0[i] = *(const bf16x8_t*)(kh + kmbase + (size_t)(kb + 64 + r) * 64 + skc);
        pk1[i] = *(const bf16x8_t*)(kl + kmbase + (size_t)(kb + 64 + r) * 64 + skc);
      }
    }
    __syncthreads();
    f32x4_t acc[4] = {};
    mfma_chunk_regB(Kb[0], Kb[1], qh_r, ql_r, acc, wm, lane);
#pragma unroll
    for (int nt = 0; nt < 4; ++nt) {
      float m0 = fmaxf(fmaxf(acc[nt][0], acc[nt][1]), fmaxf(acc[nt][2], acc[nt][3]));
      m0 = fmaxf(m0, __shfl_xor(m0, 16));
      m0 = fmaxf(m0, __shfl_xor(m0, 32));
      float mn = fmaxf(mrun[nt], m0);
      float s0 = __expf(acc[nt][0] - mn) + __expf(acc[nt][1] - mn) +
                 __expf(acc[nt][2] - mn) + __expf(acc[nt][3] - mn);
      s0 += __shfl_xor(s0, 16);
      s0 += __shfl_xor(s0, 32);
      lrun[nt] = lrun[nt] * __expf(mrun[nt] - mn) + s0;
      mrun[nt] = mn;
    }
  }
  // issue pass-2 chunk-0 prefetch (K and V) before the m/l merge section
  bf16x8_t pv0[2], pv1[2];
#pragma unroll
  for (int i = 0; i < 2; ++i) {
    int r = sr + i * 32;
    pk0[i] = *(const bf16x8_t*)(kh + kmbase + (size_t)r * 64 + skc);
    pk1[i] = *(const bf16x8_t*)(kl + kmbase + (size_t)r * 64 + skc);
    pv0[i] = *(const bf16x8_t*)(vth + vbase + (size_t)r * 1024 + skc);
    pv1[i] = *(const bf16x8_t*)(vtl + vbase + (size_t)r * 1024 + skc);
  }
  __syncthreads();
  if (quad == 0) {
#pragma unroll
    for (int nt = 0; nt < 4; ++nt) {
      mlW[wave][0][nt * 16 + l16] = mrun[nt];
      mlW[wave][1][nt * 16 + l16] = lrun[nt];
    }
  }
  __syncthreads();
  if (t < 64) {
    float m0 = mlW[0][0][t], m1 = mlW[1][0][t], m2 = mlW[2][0][t], m3 = mlW[3][0][t];
    float mm = fmaxf(fmaxf(m0, m1), fmaxf(m2, m3));
    float ll = mlW[0][1][t] * __expf(m0 - mm) + mlW[1][1][t] * __expf(m1 - mm) +
               mlW[2][1][t] * __expf(m2 - mm) + mlW[3][1][t] * __expf(m3 - mm);
    mC[t] = mm;
    lC[t] = 1.0f / ll;
  }
  __syncthreads();
  float mq[4], il[4];
#pragma unroll
  for (int nt = 0; nt < 4; ++nt) {
    mq[nt] = mC[nt * 16 + l16];
    il[nt] = lC[nt * 16 + l16];
  }

  // ---- pass 2: recompute, final P, colsum, PV. 3 barriers/chunk ----
  f32x4_t accO[4] = {};
  for (int kb = 0; kb < 1024; kb += 64) {
    __syncthreads();  // prev PV done reading Pb/Vb
#pragma unroll
    for (int i = 0; i < 2; ++i) {
      int r = sr + i * 32;
      *(bf16x8_t*)&Kb[0][r][skc] = pk0[i];
      *(bf16x8_t*)&Kb[1][r][skc] = pk1[i];
      *(bf16x8_t*)&Vb[0][r][skc] = pv0[i];
      *(bf16x8_t*)&Vb[1][r][skc] = pv1[i];
    }
    if (kb + 64 < 1024) {  // prefetch next chunk
#pragma unroll
      for (int i = 0; i < 2; ++i) {
        int r = sr + i * 32;
        pk0[i] = *(const bf16x8_t*)(kh + kmbase + (size_t)(kb + 64 + r) * 64 + skc);
        pk1[i] = *(const bf16x8_t*)(kl + kmbase + (size_t)(kb + 64 + r) * 64 + skc);
        pv0[i] = *(const bf16x8_t*)(vth + vbase + (size_t)r * 1024 + kb + 64 + skc);
        pv1[i] = *(const bf16x8_t*)(vtl + vbase + (size_t)r * 1024 + kb + 64 + skc);
      }
    }
    __syncthreads();
    f32x4_t acc[4] = {};
    mfma_chunk_regB(Kb[0], Kb[1], qh_r, ql_r, acc, wm, lane);
    float P[4][4];
#pragma unroll
    for (int nt = 0; nt < 4; ++nt)
#pragma unroll
      for (int r = 0; r < 4; ++r) P[nt][r] = __expf(acc[nt][r] - mq[nt]) * il[nt];
#pragma unroll
    for (int r = 0; r < 4; ++r) {
      float cs = P[0][r] + P[1][r] + P[2][r] + P[3][r];
      cs += __shfl_xor(cs, 1);
      cs += __shfl_xor(cs, 2);
      cs += __shfl_xor(cs, 4);
      cs += __shfl_xor(cs, 8);
      if (l16 == 0) colsum[kb + wm + quad * 4 + r] += cs;
    }
#pragma unroll
    for (int nt = 0; nt < 4; ++nt) {
      unsigned h01, l01, h23, l23;
      cvt2(P[nt][0], P[nt][1], h01, l01);
      cvt2(P[nt][2], P[nt][3], h23, l23);
      *(uint2*)&Pb[0][nt * 16 + l16][wm + quad * 4] = make_uint2(h01, h23);
      *(uint2*)&Pb[1][nt * 16 + l16][wm + quad * 4] = make_uint2(l01, l23);
    }
    __syncthreads();  // Pb visible
    mfma_chunk(Pb[0], Pb[1], Vb[0], Vb[1], accO, wm, lane);
  }
  __syncthreads();

#pragma unroll
  for (int i = 0; i < 4; ++i)
    atomicAdd(&score[pair * 1024 + t + i * 256], colsum[t + i * 256]);
  float (*Tr)[68] = reinterpret_cast<float(*)[68]>(&Pb[0][0][0]);
#pragma unroll
  for (int nt = 0; nt < 4; ++nt)
#pragma unroll
    for (int r = 0; r < 4; ++r)
      Tr[nt * 16 + l16][wm + quad * 4 + r] = accO[nt][r];
  __syncthreads();
  const int b = pair >> 2, h = pair & 3;
#pragma unroll
  for (int i = 0; i < 16; ++i) {
    int e = t + i * 256;
    int d = e >> 6, ql_ = e & 63;
    int pix = q0 + ql_;
    int iy = (pix >> 5) + 1, ix = (pix & 31) + 1;
    outc[((size_t)(b * 256 + h * 64 + d)) * 1156 + iy * 34 + ix] = cvtpack(Tr[d][ql_]);
  }
}

// ---------------- fine fused attention: single-pass online flash -----------
// Q panel in registers; K+V register-prefetched.
__global__ __launch_bounds__(256, 2) void k_attn_fine(
    const unsigned short* __restrict__ qh, const unsigned short* __restrict__ ql,
    const unsigned short* __restrict__ kh, const unsigned short* __restrict__ kl,
    const unsigned short* __restrict__ vth, const unsigned short* __restrict__ vtl,
    float* __restrict__ outf) {
  __shared__ __align__(16) unsigned short Kb[2][64][72];
  __shared__ __align__(16) unsigned short Vb[2][64][72];
  __shared__ __align__(16) unsigned short Pb[2][64][72];
  __shared__ float m_run[64], l_run[64], alphaS[64];
  __shared__ float mWc[4][64], sWc[4][64];
  const int t = threadIdx.x;
  const int q0 = blockIdx.x * 64;
  const int pair = blockIdx.y;
  const int wave = t >> 6, lane = t & 63;
  const int l16 = lane & 15, quad = lane >> 4;
  const int wm = wave * 16;
  const int sr = t >> 3, skc = (t & 7) * 8;

  const size_t qbase = ((size_t)pair * 1024 + q0) * 64;
  bf16x8_t qh_r[2][4], ql_r[2][4];
#pragma unroll
  for (int ks = 0; ks < 2; ++ks)
#pragma unroll
    for (int nt = 0; nt < 4; ++nt) {
      int row = nt * 16 + l16, col = ks * 32 + quad * 8;
      qh_r[ks][nt] = *(const bf16x8_t*)(qh + qbase + (size_t)row * 64 + col);
      ql_r[ks][nt] = *(const bf16x8_t*)(ql + qbase + (size_t)row * 64 + col);
    }
  if (t < 64) { m_run[t] = -1e30f; l_run[t] = 0.f; }

  const size_t kmbase = (size_t)pair * 1024 * 64;
  const size_t vbase = (size_t)pair * 64 * 1024;

  // prologue prefetch: chunk 0
  bf16x8_t pk0[2], pk1[2], pv0[2], pv1[2];
#pragma unroll
  for (int i = 0; i < 2; ++i) {
    int r = sr + i * 32;
    pk0[i] = *(const bf16x8_t*)(kh + kmbase + (size_t)r * 64 + skc);
    pk1[i] = *(const bf16x8_t*)(kl + kmbase + (size_t)r * 64 + skc);
    pv0[i] = *(const bf16x8_t*)(vth + vbase + (size_t)r * 1024 + skc);
    pv1[i] = *(const bf16x8_t*)(vtl + vbase + (size_t)r * 1024 + skc);
  }

  f32x4_t accO[4] = {};
  for (int kb = 0; kb < 1024; kb += 64) {
    __syncthreads();  // prev PV done reading Pb/Vb; m/l arrays consumed
#pragma unroll
    for (int i = 0; i < 2; ++i) {
      int r = sr + i * 32;
      *(bf16x8_t*)&Kb[0][r][skc] = pk0[i];
      *(bf16x8_t*)&Kb[1][r][skc] = pk1[i];
      *(bf16x8_t*)&Vb[0][r][skc] = pv0[i];
      *(bf16x8_t*)&Vb[1][r][skc] = pv1[i];
    }
    if (kb + 64 < 1024) {  // prefetch next chunk
#pragma unroll
      for (int i = 0; i < 2; ++i) {
        int r = sr + i * 32;
        pk0[i] = *(const bf16x8_t*)(kh + kmbase + (size_t)(kb + 64 + r) * 64 + skc);
        pk1[i] = *(const bf16x8_t*)(kl + kmbase + (size_t)(kb + 64 + r) * 64 + skc);
        pv0[i] = *(const bf16x8_t*)(vth + vbase + (size_t)r * 1024 + kb + 64 + skc);
        pv1[i] = *(const bf16x8_t*)(vtl + vbase + (size_t)r * 1024 + kb + 64 + skc);
      }
    }
    __syncthreads();
    f32x4_t acc[4] = {};
    mfma_chunk_regB(Kb[0], Kb[1], qh_r, ql_r, acc, wm, lane);  // S^T tile
    // per-wave k-max per q
#pragma unroll
    for (int nt = 0; nt < 4; ++nt) {
      float m0 = fmaxf(fmaxf(acc[nt][0], acc[nt][1]), fmaxf(acc[nt][2], acc[nt][3]));
      m0 = fmaxf(m0, __shfl_xor(m0, 16));
      m0 = fmaxf(m0, __shfl_xor(m0, 32));
      if (quad == 0) mWc[wave][nt * 16 + l16] = m0;
    }
    __syncthreads();
    if (t < 64) {
      float mn = fmaxf(fmaxf(fmaxf(mWc[0][t], mWc[1][t]), fmaxf(mWc[2][t], mWc[3][t])),
                       m_run[t]);
      alphaS[t] = __expf(m_run[t] - mn);
      m_run[t] = mn;
    }
    __syncthreads();
    // P = exp(s - m_new); write Pb; per-wave partial l sums; rescale accO
    float P[4][4];
#pragma unroll
    for (int nt = 0; nt < 4; ++nt) {
      float mn = m_run[nt * 16 + l16];
#pragma unroll
      for (int r = 0; r < 4; ++r) P[nt][r] = __expf(acc[nt][r] - mn);
      float s0 = P[nt][0] + P[nt][1] + P[nt][2] + P[nt][3];
      s0 += __shfl_xor(s0, 16);
      s0 += __shfl_xor(s0, 32);
      if (quad == 0) sWc[wave][nt * 16 + l16] = s0;
      unsigned h01, l01, h23, l23;
      cvt2(P[nt][0], P[nt][1], h01, l01);
      cvt2(P[nt][2], P[nt][3], h23, l23);
      *(uint2*)&Pb[0][nt * 16 + l16][wm + quad * 4] = make_uint2(h01, h23);
      *(uint2*)&Pb[1][nt * 16 + l16][wm + quad * 4] = make_uint2(l01, l23);
    }
#pragma unroll
    for (int r = 0; r < 4; ++r) {
      float a = alphaS[wm + quad * 4 + r];
#pragma unroll
      for (int nt = 0; nt < 4; ++nt) accO[nt][r] *= a;
    }
    __syncthreads();  // Pb + sWc visible
    if (t < 64)
      l_run[t] = l_run[t] * alphaS[t] + (sWc[0][t] + sWc[1][t] + sWc[2][t] + sWc[3][t]);
    mfma_chunk(Pb[0], Pb[1], Vb[0], Vb[1], accO, wm, lane);  // O += P~ @ V
  }
  __syncthreads();
#pragma unroll
  for (int r = 0; r < 4; ++r) {
    float invl = 1.0f / l_run[wm + quad * 4 + r];
    int qm = q0 + wm + quad * 4 + r;
#pragma unroll
    for (int nt = 0; nt < 4; ++nt)
      outf[((size_t)pair * 1024 + qm) * 64 + nt * 16 + l16] = accO[nt][r] * invl;
  }
}

// ---------------- per-pair top-256 via bitonic sort ------------------------
__global__ __launch_bounds__(256) void k_topk(
    const float* __restrict__ score, int* __restrict__ idx) {
  __shared__ unsigned long long key[1024];
  const int pair = blockIdx.x;
  const int t = threadIdx.x;
#pragma unroll
  for (int j = 0; j < 4; ++j) {
    int i = t + j * 256;
    unsigned u = __float_as_uint(score[pair * 1024 + i]);
    u = u ^ ((u & 0x80000000u) ? 0xFFFFFFFFu : 0x80000000u);
    u = ~u;
    key[i] = ((unsigned long long)u << 32) | (unsigned)i;
  }
  __syncthreads();
  for (int k = 2; k <= 1024; k <<= 1) {
    for (int j = k >> 1; j > 0; j >>= 1) {
      for (int w = 0; w < 4; ++w) {
        int i = t + w * 256;
        int l = i ^ j;
        if (l > i) {
          bool up = ((i & k) == 0);
          unsigned long long a = key[i], b = key[l];
          if ((a > b) == up) { key[i] = b; key[l] = a; }
        }
      }
      __syncthreads();
    }
  }
  idx[pair * 256 + t] = (int)(key[t] & 0xFFFFFFFFu);
}

// ---------------- convT: 64oc x 64pix tile, 4 classes, dbuf ----------------
__global__ __launch_bounds__(256) void k_convT_mfma(
    const unsigned* __restrict__ inp, const unsigned short* __restrict__ wth,
    const unsigned short* __restrict__ wtl, const float* __restrict__ bias,
    float* __restrict__ out) {
  __shared__ unsigned short Ah[2][64][72], Al[2][64][72];
  __shared__ unsigned short Bh[2][64][72], Bl[2][64][72];
  const int t = threadIdx.x;
  const int pix0 = blockIdx.x * 64;
  const int oc0 = blockIdx.y * 64;
  const int cls = blockIdx.z;
  const int ry = cls >> 1, rx = cls & 1;
  const int b = pix0 >> 10;
  const int wave = t >> 6, lane = t & 63;
  const int l16 = lane & 15, quad = lane >> 4;
  const int wm = (wave & 1) * 32, wn = (wave >> 1) * 32;
  const int pl = t & 63, icg = t >> 6;
  const int remg = (pix0 + pl) & 1023;
  const int tyy = remg >> 5, txx = remg & 31;
  const int ar = t >> 2, ac = (t & 3) * 16;
  const size_t wbase = ((size_t)cls * 256 + oc0 + ar) * 1024 + ac;
  f32x4_t acc[2][2] = {};
  bf16x8_t a0, a1, a2, a3;
  unsigned u[16];
  // prologue: chunk kb=0 (tap 0 -> tk=0, txi=0; ic0=0)
  {
    const int iy = tyy + ry + 1, ix = txx + rx + 1;
    const unsigned* p = inp + (size_t)(b * 256 + icg * 16) * 1156 + iy * 34 + ix;
#pragma unroll
    for (int j = 0; j < 16; ++j) u[j] = p[(size_t)j * 1156];
    a0 = *(const bf16x8_t*)(wth + wbase);
    a1 = *(const bf16x8_t*)(wth + wbase + 8);
    a2 = *(const bf16x8_t*)(wtl + wbase);
    a3 = *(const bf16x8_t*)(wtl + wbase + 8);
  }
  int cur = 0;
  for (int kb = 0; kb < 1024; kb += 64) {
    unsigned hp[8], lpk[8];
#pragma unroll
    for (int j = 0; j < 8; ++j) {
      hp[j] = pk_h(u[2 * j], u[2 * j + 1]);
      lpk[j] = pk_l(u[2 * j], u[2 * j + 1]);
    }
    *(bf16x8_t*)&Ah[cur][ar][ac] = a0;
    *(bf16x8_t*)&Ah[cur][ar][ac + 8] = a1;
    *(bf16x8_t*)&Al[cur][ar][ac] = a2;
    *(bf16x8_t*)&Al[cur][ar][ac + 8] = a3;
    *(uint4*)&Bh[cur][pl][icg * 16] = make_uint4(hp[0], hp[1], hp[2], hp[3]);
    *(uint4*)&Bh[cur][pl][icg * 16 + 8] = make_uint4(hp[4], hp[5], hp[6], hp[7]);
    *(uint4*)&Bl[cur][pl][icg * 16] = make_uint4(lpk[0], lpk[1], lpk[2], lpk[3]);
    *(uint4*)&Bl[cur][pl][icg * 16 + 8] = make_uint4(lpk[4], lpk[5], lpk[6], lpk[7]);
    if (kb + 64 < 1024) {  // prefetch next chunk into registers
      const int kn = kb + 64;
      const int tap = kn >> 8, ic0 = kn & 255;
      const int tk = tap >> 1, txi = tap & 1;
      const int iy = tyy + ry + 1 - tk, ix = txx + rx + 1 - txi;
      const unsigned* p = inp + (size_t)(b * 256 + ic0 + icg * 16) * 1156 + iy * 34 + ix;
#pragma unroll
      for (int j = 0; j < 16; ++j) u[j] = p[(size_t)j * 1156];
      a0 = *(const bf16x8_t*)(wth + wbase + kn);
      a1 = *(const bf16x8_t*)(wth + wbase + kn + 8);
      a2 = *(const bf16x8_t*)(wtl + wbase + kn);
      a3 = *(const bf16x8_t*)(wtl + wbase + kn + 8);
    }
    __syncthreads();
    mfma_tile2x2(Ah[cur], Al[cur], Bh[cur], Bl[cur], acc, wm, wn, lane);
    cur ^= 1;
  }
#pragma unroll
  for (int mt = 0; mt < 2; ++mt)
#pragma unroll
    for (int r = 0; r < 4; ++r) {
      int oc = oc0 + wm + mt * 16 + quad * 4 + r;
      float bvs = bias[oc];
#pragma unroll
      for (int nt = 0; nt < 2; ++nt) {
        int pix = pix0 + wn + nt * 16 + l16;
        int rem2 = pix & 1023;
        int y = (rem2 >> 5) * 2 + ry, xx = (rem2 & 31) * 2 + rx;
        out[((size_t)(b * 256 + oc) * 64 + y) * 64 + xx] = acc[mt][nt][r] + bvs;
      }
    }
}

// ---------------- scatter fine outputs into y ------------------------------
__global__ __launch_bounds__(256) void k_scatter(
    const float* __restrict__ outf, const int* __restrict__ idx,
    float* __restrict__ y) {
  int g = blockIdx.x * 256 + threadIdx.x;
  int pair = g >> 16;
  int rem = g & 65535;
  int tok = rem >> 6, d = rem & 63;
  int b = pair >> 2, h = pair & 3;
  int pp = idx[pair * 256 + (tok >> 2)];
  int py = (tok >> 1) & 1, px = tok & 1;
  int ry = (pp >> 5) * 2 + py, rx = (pp & 31) * 2 + px;
  y[((size_t)(b * 256 + h * 64 + d) * 64 + ry) * 64 + rx] += outf[g];
}

// ---------------- depthwise 3x3 + BN + relu6 -> packed yd ------------------
__global__ __launch_bounds__(256) void k_dwconv(
    const float* __restrict__ y, const float* __restrict__ wdw,
    const float* __restrict__ g, const float* __restrict__ bb,
    const float* __restrict__ m, const float* __restrict__ vv,
    unsigned* __restrict__ ydhl) {
  int gi = blockIdx.x * 256 + threadIdx.x;
  int x = gi & 63, yy = (gi >> 6) & 63, ch = (gi >> 12) & 255, b = gi >> 20;
  const float* plane = y + (size_t)(b * 256 + ch) * 4096;
  const float* wc = wdw + ch * 9;
  float s = 0.f;
#pragma unroll
  for (int ky = 0; ky < 3; ++ky) {
    int iy = yy + ky - 1;
    if (iy < 0 || iy >= 64) continue;
#pragma unroll
    for (int kx = 0; kx < 3; ++kx) {
      int ix = x + kx - 1;
      if (ix < 0 || ix >= 64) continue;
      s = fmaf(plane[iy * 64 + ix], wc[ky * 3 + kx], s);
    }
  }
  float sc = g[ch] * rsqrtf(vv[ch] + EPS_);
  float val = s * sc + (bb[ch] - m[ch] * sc);
  ydhl[gi] = cvtpack(fminf(fmaxf(val, 0.f), 6.f));
}

// ---------------- pointwise 1x1 + BN + relu6, 64oc x 64pix, dbuf -----------
__global__ __launch_bounds__(256) void k_pw_mfma(
    const unsigned* __restrict__ ydhl, const unsigned short* __restrict__ wh,
    const unsigned short* __restrict__ wl, const float* __restrict__ g,
    const float* __restrict__ bb, const float* __restrict__ m,
    const float* __restrict__ vv, float* __restrict__ out) {
  __shared__ unsigned short Ah[2][64][72], Al[2][64][72];
  __shared__ unsigned short Bh[2][64][72], Bl[2][64][72];
  const int t = threadIdx.x;
  const int pix0 = blockIdx.x * 64;
  const int oc0 = blockIdx.y * 64;
  const int b = pix0 >> 12, pos0 = pix0 & 4095;
  const int wave = t >> 6, lane = t & 63;
  const int l16 = lane & 15, quad = lane >> 4;
  const int wm = (wave & 1) * 32, wn = (wave >> 1) * 32;
  const int pl = t & 63, icg = t >> 6;
  const int ar = t >> 2, ac = (t & 3) * 16;
  f32x4_t acc[2][2] = {};
  bf16x8_t a0, a1, a2, a3;
  unsigned u[16];
  // prologue: chunk kb=0
  {
    const unsigned* p = ydhl + (size_t)(b * 256 + icg * 16) * 4096 + pos0 + pl;
#pragma unroll
    for (int j = 0; j < 16; ++j) u[j] = p[(size_t)j * 4096];
    a0 = *(const bf16x8_t*)(wh + (size_t)(oc0 + ar) * 256 + ac);
    a1 = *(const bf16x8_t*)(wh + (size_t)(oc0 + ar) * 256 + ac + 8);
    a2 = *(const bf16x8_t*)(wl + (size_t)(oc0 + ar) * 256 + ac);
    a3 = *(const bf16x8_t*)(wl + (size_t)(oc0 + ar) * 256 + ac + 8);
  }
  int cur = 0;
  for (int kb = 0; kb < 256; kb += 64) {
    unsigned hp[8], lpk[8];
#pragma unroll
    for (int j = 0; j < 8; ++j) {
      hp[j] = pk_h(u[2 * j], u[2 * j + 1]);
      lpk[j] = pk_l(u[2 * j], u[2 * j + 1]);
    }
    *(bf16x8_t*)&Ah[cur][ar][ac] = a0;
    *(bf16x8_t*)&Ah[cur][ar][ac + 8] = a1;
    *(bf16x8_t*)&Al[cur][ar][ac] = a2;
    *(bf16x8_t*)&Al[cur][ar][ac + 8] = a3;
    *(uint4*)&Bh[cur][pl][icg * 16] = make_uint4(hp[0], hp[1], hp[2], hp[3]);
    *(uint4*)&Bh[cur][pl][icg * 16 + 8] = make_uint4(hp[4], hp[5], hp[6], hp[7]);
    *(uint4*)&Bl[cur][pl][icg * 16] = make_uint4(lpk[0], lpk[1], lpk[2], lpk[3]);
    *(uint4*)&Bl[cur][pl][icg * 16 + 8] = make_uint4(lpk[4], lpk[5], lpk[6], lpk[7]);
    if (kb + 64 < 256) {  // prefetch next chunk into registers
      const int kn = kb + 64;
      const unsigned* p = ydhl + (size_t)(b * 256 + kn + icg * 16) * 4096 + pos0 + pl;
#pragma unroll
      for (int j = 0; j < 16; ++j) u[j] = p[(size_t)j * 4096];
      a0 = *(const bf16x8_t*)(wh + (size_t)(oc0 + ar) * 256 + kn + ac);
      a1 = *(const bf16x8_t*)(wh + (size_t)(oc0 + ar) * 256 + kn + ac + 8);
      a2 = *(const bf16x8_t*)(wl + (size_t)(oc0 + ar) * 256 + kn + ac);
      a3 = *(const bf16x8_t*)(wl + (size_t)(oc0 + ar) * 256 + kn + ac + 8);
    }
    __syncthreads();
    mfma_tile2x2(Ah[cur], Al[cur], Bh[cur], Bl[cur], acc, wm, wn, lane);
    cur ^= 1;
  }
#pragma unroll
  for (int mt = 0; mt < 2; ++mt)
#pragma unroll
    for (int r = 0; r < 4; ++r) {
      int oc = oc0 + wm + mt * 16 + quad * 4 + r;
      float sc = g[oc] * rsqrtf(vv[oc] + EPS_);
      float off = bb[oc] - m[oc] * sc;
#pragma unroll
      for (int nt = 0; nt < 2; ++nt) {
        int pix = pos0 + wn + nt * 16 + l16;
        float val = fminf(fmaxf(acc[mt][nt][r] * sc + off, 0.f), 6.f);
        out[(size_t)(b * 256 + oc) * 4096 + pix] = val;
      }
    }
}

// ---------------------------------------------------------------------------
extern "C" void kernel_launch(void* const* d_in, const int* in_sizes, int n_in,
                              void* d_out, int out_size, void* d_ws, size_t ws_size,
                              hipStream_t stream) {
  (void)in_sizes; (void)n_in; (void)out_size; (void)ws_size;
  const float* x       = (const float*)d_in[0];
  const float* w_down  = (const float*)d_in[1];
  const float* b_down  = (const float*)d_in[2];
  const float* w_qkv_c = (const float*)d_in[3];
  const float* b_qkv_c = (const float*)d_in[4];
  const float* w_up    = (const float*)d_in[5];
  const float* b_up    = (const float*)d_in[6];
  const float* w_qkv_f = (const float*)d_in[7];
  const float* b_qkv_f = (const float*)d_in[8];
  const float* w_dw    = (const float*)d_in[9];
  const float* bn_dw_g = (const float*)d_in[10];
  const float* bn_dw_b = (const float*)d_in[11];
  const float* bn_dw_m = (const float*)d_in[12];
  const float* bn_dw_v = (const float*)d_in[13];
  const float* w_pw    = (const float*)d_in[14];
  const float* bn_pw_g = (const float*)d_in[15];
  const float* bn_pw_b = (const float*)d_in[16];
  const float* bn_pw_m = (const float*)d_in[17];
  const float* bn_pw_v = (const float*)d_in[18];

  float* ws = (float*)d_ws;  // offsets in 4-byte units (round 6/8 layout)
  unsigned*       xphl   = (unsigned*)ws;                   // 9,191,424 u
  unsigned*       ydhl   = (unsigned*)ws;                   // alias (xphl dead by then)
  unsigned short* qh     = (unsigned short*)(ws + 33554432);
  unsigned short* ql     = (unsigned short*)(ws + 34603008);
  unsigned short* kh     = (unsigned short*)(ws + 35651584);
  unsigned short* kl     = (unsigned short*)(ws + 36700160);
  unsigned short* vth    = (unsigned short*)(ws + 37748736);
  unsigned short* vtl    = (unsigned short*)(ws + 38797312);
  unsigned*       xdhl   = (unsigned*)(ws + 39845888);      // 2,097,152 u
  unsigned*       outcphl= (unsigned*)(ws + 41943040);      // 2,367,488 u
  float*          coarse = ws + 44310528;                   // 8,388,608 f
  float*          outf   = ws + 52699136;                   // 2,097,152 f
  float*          score  = ws + 54796288;                   // 32,768 f
  unsigned short* wdh    = (unsigned short*)(ws + 54829056);
  unsigned short* wdl    = (unsigned short*)(ws + 55353344);
  unsigned short* wt_hi  = (unsigned short*)(ws + 55877632);
  unsigned short* wt_lo  = (unsigned short*)(ws + 56401920);
  unsigned short* wpw_hi = (unsigned short*)(ws + 56926208);
  unsigned short* wpw_lo = (unsigned short*)(ws + 56958976);
  unsigned short* wqh_c  = (unsigned short*)(ws + 56991744);
  unsigned short* wql_c  = (unsigned short*)(ws + 56997888);
  unsigned short* wqh_f  = (unsigned short*)(ws + 57004032);
  unsigned short* wql_f  = (unsigned short*)(ws + 57010176);
  int*            idx    = (int*)(ws + 57016320);           // 8,192 int

  hipMemsetAsync(score, 0, 32768 * sizeof(float), stream);
  hipMemsetAsync(outcphl, 0, (size_t)2367488 * sizeof(unsigned), stream);
  k_pad_x<<<2048, 256, 0, stream>>>(x, xphl);
  k_cvt_wdown<<<4096, 256, 0, stream>>>(w_down, wdh, wdl);
  k_cvt_wqkv<<<48, 256, 0, stream>>>(w_qkv_c, wqh_c, wql_c);
  k_cvt_wqkv<<<48, 256, 0, stream>>>(w_qkv_f, wqh_f, wql_f);
  k_cvt_wup<<<4096, 256, 0, stream>>>(w_up, wt_hi, wt_lo);
  k_cvt_wpw<<<256, 256, 0, stream>>>(w_pw, wpw_hi, wpw_lo);

  k_conv_down_mfma<<<dim3(128, 4), 256, 0, stream>>>(xphl, wdh, wdl, b_down, xdhl);
  k_qkv_mfma<0><<<dim3(16, 32), 256, 0, stream>>>(xdhl, nullptr, wqh_c, wql_c, b_qkv_c,
                                                  nullptr, qh, ql, kh, kl, vth, vtl);
  k_attn_coarse<<<dim3(16, 32), 256, 0, stream>>>(qh, ql, kh, kl, vth, vtl, score, outcphl);
  k_topk<<<32, 256, 0, stream>>>(score, idx);
  k_convT_mfma<<<dim3(128, 4, 4), 256, 0, stream>>>(outcphl, wt_hi, wt_lo, b_up, coarse);

  k_qkv_mfma<1><<<dim3(16, 32), 256, 0, stream>>>(nullptr, coarse, wqh_f, wql_f, b_qkv_f,
                                                  idx, qh, ql, kh, kl, vth, vtl);
  k_attn_fine<<<dim3(16, 32), 256, 0, stream>>>(qh, ql, kh, kl, vth, vtl, outf);
  k_scatter<<<8192, 256, 0, stream>>>(outf, idx, coarse);
  k_dwconv<<<32768, 256, 0, stream>>>(coarse, w_dw, bn_dw_g, bn_dw_b, bn_dw_m, bn_dw_v, ydhl);
  k_pw_mfma<<<dim3(512, 4), 256, 0, stream>>>(ydhl, wpw_hi, wpw_lo, bn_pw_g, bn_pw_b,
                                              bn_pw_m, bn_pw_v, (float*)d_out);
}

// Round 4
// 590.899 us; speedup vs baseline: 1.0265x; 1.0265x over previous
//
#include <hip/hip_runtime.h>
#include <cstdint>
#include <cstddef>

// ---------------------------------------------------------------------------
// RegionSelectionAttention. Round 13: revert round-12's convT/pw 64x64
// retile (regression: halved tiles doubled per-pixel weight traffic and
// chunk count with no occupancy gain). convT/pw back to 128-pix 2-barrier
// reg-prefetch form. conv_down keeps double-buffered single-barrier loop.
// Attention keeps Q-in-registers. Arithmetic unchanged (bit-identical).
// ---------------------------------------------------------------------------

#define EPS_ 1e-5f

typedef short bf16x8_t __attribute__((ext_vector_type(8)));
typedef float f32x4_t __attribute__((ext_vector_type(4)));
#define MFMA16(a, b, c) __builtin_amdgcn_mfma_f32_16x16x32_bf16(a, b, c, 0, 0, 0)

__device__ __forceinline__ void cvt1(float f, unsigned short& h, unsigned short& l) {
  unsigned u = __float_as_uint(f);
  unsigned r = u + 0x7FFFu + ((u >> 16) & 1u);
  h = (unsigned short)(r >> 16);
  float lo = f - __uint_as_float(r & 0xFFFF0000u);
  l = (unsigned short)(__float_as_uint(lo) >> 16);
}
__device__ __forceinline__ unsigned cvtpack(float f) {
  unsigned short h, l;
  cvt1(f, h, l);
  return (unsigned)h | ((unsigned)l << 16);
}
__device__ __forceinline__ void cvt2(float f0, float f1, unsigned& hpack, unsigned& lpack) {
  unsigned u0 = __float_as_uint(f0), u1 = __float_as_uint(f1);
  unsigned r0 = u0 + 0x7FFFu + ((u0 >> 16) & 1u);
  unsigned r1 = u1 + 0x7FFFu + ((u1 >> 16) & 1u);
  hpack = (r0 >> 16) | (r1 & 0xFFFF0000u);
  float l0 = f0 - __uint_as_float(r0 & 0xFFFF0000u);
  float l1 = f1 - __uint_as_float(r1 & 0xFFFF0000u);
  lpack = (__float_as_uint(l0) >> 16) | (__float_as_uint(l1) & 0xFFFF0000u);
}
__device__ __forceinline__ unsigned pk_h(unsigned a, unsigned b) {
  return (a & 0xFFFFu) | (b << 16);
}
__device__ __forceinline__ unsigned pk_l(unsigned a, unsigned b) {
  return (a >> 16) | (b & 0xFFFF0000u);
}

// ---------------- pad x -> packed xphl[plane][66 rows x stride 68] ---------
__global__ __launch_bounds__(256) void k_pad_x(
    const float* __restrict__ x, unsigned* __restrict__ xphl) {
  const int plane = blockIdx.x;  // 2048
  const float* src = x + (size_t)plane * 4096;
  unsigned* dst = xphl + (size_t)plane * 4488;
  for (int e = threadIdx.x; e < 4356; e += 256) {
    int r = e / 66, cc = e - r * 66;
    float v = 0.f;
    if (r >= 1 && r <= 64 && cc >= 1 && cc <= 64) v = src[(r - 1) * 64 + (cc - 1)];
    dst[r * 68 + cc] = cvtpack(v);
  }
}

// ---------------- weight conversions ---------------------------------------
__global__ __launch_bounds__(256) void k_cvt_wdown(
    const float* __restrict__ w, unsigned short* __restrict__ wh,
    unsigned short* __restrict__ wl) {
  int e = blockIdx.x * 256 + threadIdx.x;  // 1,048,576: [oc][4096]
  cvt1(w[e], wh[e], wl[e]);
}

__global__ __launch_bounds__(256) void k_cvt_wqkv(
    const float* __restrict__ wq, unsigned short* __restrict__ wh,
    unsigned short* __restrict__ wl) {
  int e = blockIdx.x * 256 + threadIdx.x;  // 12288: [col][d]
  int col = e >> 6, d = e & 63;
  float f = wq[d * 192 + col];
  if (col < 64) f *= 0.125f;  // fold attn scale into q (pow2: exact)
  cvt1(f, wh[e], wl[e]);
}

__global__ __launch_bounds__(256) void k_cvt_wup(
    const float* __restrict__ w_up, unsigned short* __restrict__ wth,
    unsigned short* __restrict__ wtl) {
  int e = blockIdx.x * 256 + threadIdx.x;  // 2^20: [class][oc][kp=tap*256+ic]
  int kp = e & 1023, oc = (e >> 10) & 255, c = e >> 18;
  int tap = kp >> 8, ic = kp & 255;
  int tk = tap >> 1, txi = tap & 1;
  int ry = c >> 1, rx = c & 1;
  int ky = (1 - ry) + 2 * tk, kx = (1 - rx) + 2 * txi;
  cvt1(w_up[((size_t)(ic * 256 + oc) * 4 + ky) * 4 + kx], wth[e], wtl[e]);
}

__global__ __launch_bounds__(256) void k_cvt_wpw(
    const float* __restrict__ w, unsigned short* __restrict__ wh,
    unsigned short* __restrict__ wl) {
  int e = blockIdx.x * 256 + threadIdx.x;  // 65536 [oc][ic]
  cvt1(w[e], wh[e], wl[e]);
}

// ====================== MFMA cores =========================================
__device__ __forceinline__ void mfma_chunk(
    const unsigned short (*Ah)[72], const unsigned short (*Al)[72],
    const unsigned short (*Bh)[72], const unsigned short (*Bl)[72],
    f32x4_t (&acc)[4], int wm, int lane) {
  const int l16 = lane & 15, quad = lane >> 4;
#pragma unroll
  for (int ks = 0; ks < 2; ++ks) {
    int ko = ks * 32 + quad * 8;
    bf16x8_t ah = *(const bf16x8_t*)&Ah[wm + l16][ko];
    bf16x8_t al = *(const bf16x8_t*)&Al[wm + l16][ko];
#pragma unroll
    for (int nt = 0; nt < 4; ++nt) {
      bf16x8_t bh = *(const bf16x8_t*)&Bh[nt * 16 + l16][ko];
      bf16x8_t bl = *(const bf16x8_t*)&Bl[nt * 16 + l16][ko];
      acc[nt] = MFMA16(ah, bh, acc[nt]);
      acc[nt] = MFMA16(ah, bl, acc[nt]);
      acc[nt] = MFMA16(al, bh, acc[nt]);
    }
  }
}

// S-stage with the loop-invariant Q panel held in registers (B operand).
__device__ __forceinline__ void mfma_chunk_regB(
    const unsigned short (*Ah)[72], const unsigned short (*Al)[72],
    const bf16x8_t (&bh)[2][4], const bf16x8_t (&bl)[2][4],
    f32x4_t (&acc)[4], int wm, int lane) {
  const int l16 = lane & 15, quad = lane >> 4;
#pragma unroll
  for (int ks = 0; ks < 2; ++ks) {
    int ko = ks * 32 + quad * 8;
    bf16x8_t ah = *(const bf16x8_t*)&Ah[wm + l16][ko];
    bf16x8_t al = *(const bf16x8_t*)&Al[wm + l16][ko];
#pragma unroll
    for (int nt = 0; nt < 4; ++nt) {
      acc[nt] = MFMA16(ah, bh[ks][nt], acc[nt]);
      acc[nt] = MFMA16(ah, bl[ks][nt], acc[nt]);
      acc[nt] = MFMA16(al, bh[ks][nt], acc[nt]);
    }
  }
}

__device__ __forceinline__ void mfma_tile2x2(
    const unsigned short (*Ah)[72], const unsigned short (*Al)[72],
    const unsigned short (*Bh)[72], const unsigned short (*Bl)[72],
    f32x4_t (&acc)[2][2], int wm, int wn, int lane) {
  const int l16 = lane & 15, quad = lane >> 4;
#pragma unroll
  for (int ks = 0; ks < 2; ++ks) {
    int ko = ks * 32 + quad * 8;
    bf16x8_t ah[2], al[2];
#pragma unroll
    for (int mt = 0; mt < 2; ++mt) {
      ah[mt] = *(const bf16x8_t*)&Ah[wm + mt * 16 + l16][ko];
      al[mt] = *(const bf16x8_t*)&Al[wm + mt * 16 + l16][ko];
    }
#pragma unroll
    for (int nt = 0; nt < 2; ++nt) {
      bf16x8_t bh = *(const bf16x8_t*)&Bh[wn + nt * 16 + l16][ko];
      bf16x8_t bl = *(const bf16x8_t*)&Bl[wn + nt * 16 + l16][ko];
#pragma unroll
      for (int mt = 0; mt < 2; ++mt) {
        acc[mt][nt] = MFMA16(ah[mt], bh, acc[mt][nt]);
        acc[mt][nt] = MFMA16(ah[mt], bl, acc[mt][nt]);
        acc[mt][nt] = MFMA16(al[mt], bh, acc[mt][nt]);
      }
    }
  }
}

__device__ __forceinline__ void mfma_tile2x4(
    const unsigned short (*Ah)[72], const unsigned short (*Al)[72],
    const unsigned short (*Bh)[72], const unsigned short (*Bl)[72],
    f32x4_t (&acc)[2][4], int wm, int wn, int lane) {
  const int l16 = lane & 15, quad = lane >> 4;
#pragma unroll
  for (int ks = 0; ks < 2; ++ks) {
    int ko = ks * 32 + quad * 8;
    bf16x8_t ah[2], al[2];
#pragma unroll
    for (int mt = 0; mt < 2; ++mt) {
      ah[mt] = *(const bf16x8_t*)&Ah[wm + mt * 16 + l16][ko];
      al[mt] = *(const bf16x8_t*)&Al[wm + mt * 16 + l16][ko];
    }
#pragma unroll
    for (int nt = 0; nt < 4; ++nt) {
      bf16x8_t bh = *(const bf16x8_t*)&Bh[wn + nt * 16 + l16][ko];
      bf16x8_t bl = *(const bf16x8_t*)&Bl[wn + nt * 16 + l16][ko];
#pragma unroll
      for (int mt = 0; mt < 2; ++mt) {
        acc[mt][nt] = MFMA16(ah[mt], bh, acc[mt][nt]);
        acc[mt][nt] = MFMA16(ah[mt], bl, acc[mt][nt]);
        acc[mt][nt] = MFMA16(al[mt], bh, acc[mt][nt]);
      }
    }
  }
}

// ---------------- conv down k4 s2 p1, 64oc x 64pix, 2x2 waves, K=4096 ------
// Double-buffered LDS, one barrier per chunk.
__global__ __launch_bounds__(256) void k_conv_down_mfma(
    const unsigned* __restrict__ xphl, const unsigned short* __restrict__ wdh,
    const unsigned short* __restrict__ wdl, const float* __restrict__ bias,
    unsigned* __restrict__ xdhl) {
  __shared__ unsigned short Ah[2][64][72], Al[2][64][72];
  __shared__ unsigned short Bh[2][64][72], Bl[2][64][72];
  const int t = threadIdx.x;
  const int pix0 = blockIdx.x * 64, oc0 = blockIdx.y * 64;
  const int bimg = pix0 >> 10, pos = pix0 & 1023;
  const int pl = t & 63, icg = t >> 6;
  const int rem = (pix0 + pl) & 1023;
  const int oy = rem >> 5, ox = rem & 31;
  const unsigned* xb = xphl + ((size_t)bimg * 256 + icg) * 4488 + (oy * 2) * 68 + ox * 2;
  const int wave = t >> 6, lane = t & 63, l16 = lane & 15, quad = lane >> 4;
  const int wm = (wave & 1) * 32, wn = (wave >> 1) * 32;
  const int ar = t >> 2, ac = (t & 3) * 16;
  const unsigned short* wra = wdh + (size_t)(oc0 + ar) * 4096 + ac;
  const unsigned short* wrl = wdl + (size_t)(oc0 + ar) * 4096 + ac;
  f32x4_t acc[2][2] = {};
  bf16x8_t a0, a1, a2, a3;
  uint2 u01[4], u23[4];
  // prologue: chunk kb=0
  a0 = *(const bf16x8_t*)(wra);
  a1 = *(const bf16x8_t*)(wra + 8);
  a2 = *(const bf16x8_t*)(wrl);
  a3 = *(const bf16x8_t*)(wrl + 8);
#pragma unroll
  for (int r = 0; r < 4; ++r) {
    u01[r] = *(const uint2*)(xb + r * 68);
    u23[r] = *(const uint2*)(xb + r * 68 + 2);
  }
  int cur = 0;
  for (int kb = 0; kb < 4096; kb += 64) {
    unsigned hp[8], lp[8];
#pragma unroll
    for (int r = 0; r < 4; ++r) {
      hp[2 * r]     = pk_h(u01[r].x, u01[r].y);
      lp[2 * r]     = pk_l(u01[r].x, u01[r].y);
      hp[2 * r + 1] = pk_h(u23[r].x, u23[r].y);
      lp[2 * r + 1] = pk_l(u23[r].x, u23[r].y);
    }
    *(bf16x8_t*)&Ah[cur][ar][ac] = a0;
    *(bf16x8_t*)&Ah[cur][ar][ac + 8] = a1;
    *(bf16x8_t*)&Al[cur][ar][ac] = a2;
    *(bf16x8_t*)&Al[cur][ar][ac + 8] = a3;
    *(uint4*)&Bh[cur][pl][icg * 16] = make_uint4(hp[0], hp[1], hp[2], hp[3]);
    *(uint4*)&Bh[cur][pl][icg * 16 + 8] = make_uint4(hp[4], hp[5], hp[6], hp[7]);
    *(uint4*)&Bl[cur][pl][icg * 16] = make_uint4(lp[0], lp[1], lp[2], lp[3]);
    *(uint4*)&Bl[cur][pl][icg * 16 + 8] = make_uint4(lp[4], lp[5], lp[6], lp[7]);
    if (kb + 64 < 4096) {  // prefetch next chunk into registers
      xb += 4 * 4488;
      a0 = *(const bf16x8_t*)(wra + kb + 64);
      a1 = *(const bf16x8_t*)(wra + kb + 64 + 8);
      a2 = *(const bf16x8_t*)(wrl + kb + 64);
      a3 = *(const bf16x8_t*)(wrl + kb + 64 + 8);
#pragma unroll
      for (int r = 0; r < 4; ++r) {
        u01[r] = *(const uint2*)(xb + r * 68);
        u23[r] = *(const uint2*)(xb + r * 68 + 2);
      }
    }
    __syncthreads();  // buf[cur] writes visible; prior reads of buf[cur] done
    mfma_tile2x2(Ah[cur], Al[cur], Bh[cur], Bl[cur], acc, wm, wn, lane);
    cur ^= 1;
  }
#pragma unroll
  for (int mt = 0; mt < 2; ++mt)
#pragma unroll
    for (int r = 0; r < 4; ++r) {
      int oc = oc0 + wm + mt * 16 + quad * 4 + r;
      float bv = bias[oc];
#pragma unroll
      for (int nt = 0; nt < 2; ++nt)
        xdhl[((size_t)(bimg * 256 + oc)) * 1024 + pos + wn + nt * 16 + l16] =
            cvtpack(acc[mt][nt][r] + bv);
    }
}

// ---------------- qkv projection -------------------------------------------
template <int MODE>
__global__ __launch_bounds__(256) void k_qkv_mfma(
    const unsigned* __restrict__ srcp, const float* __restrict__ srcf,
    const unsigned short* __restrict__ wh, const unsigned short* __restrict__ wl,
    const float* __restrict__ bq, const int* __restrict__ topk,
    unsigned short* __restrict__ qh, unsigned short* __restrict__ ql,
    unsigned short* __restrict__ kh, unsigned short* __restrict__ kl,
    unsigned short* __restrict__ vth, unsigned short* __restrict__ vtl) {
  __shared__ unsigned short Ah[64][72], Al[64][72];
  const int t = threadIdx.x;
  const int tok0 = blockIdx.x * 64;
  const int pair = blockIdx.y;
  const int b = pair >> 2, h = pair & 3;
  const int tokl = t & 63, dg = t >> 6;
  unsigned hp[8], lp[8];
  if (MODE == 0) {
    const unsigned* base = srcp + ((size_t)(b * 256 + h * 64 + dg * 16)) * 1024 + tok0 + tokl;
    unsigned u[16];
#pragma unroll
    for (int j = 0; j < 16; ++j) u[j] = base[(size_t)j * 1024];
#pragma unroll
    for (int j = 0; j < 8; ++j) {
      hp[j] = pk_h(u[2 * j], u[2 * j + 1]);
      lp[j] = pk_l(u[2 * j], u[2 * j + 1]);
    }
  } else {
    int tok = tok0 + tokl;
    int pp = topk[pair * 256 + (tok >> 2)];
    int py = (tok >> 1) & 1, px = tok & 1;
    int ry = (pp >> 5) * 2 + py, rx = (pp & 31) * 2 + px;
    const float* base = srcf + ((size_t)(b * 256 + h * 64 + dg * 16)) * 4096 + ry * 64 + rx;
    float fv[16];
#pragma unroll
    for (int j = 0; j < 16; ++j) fv[j] = base[(size_t)j * 4096];
#pragma unroll
    for (int j = 0; j < 8; ++j) cvt2(fv[2 * j], fv[2 * j + 1], hp[j], lp[j]);
  }
  *(uint4*)&Ah[tokl][dg * 16] = make_uint4(hp[0], hp[1], hp[2], hp[3]);
  *(uint4*)&Ah[tokl][dg * 16 + 8] = make_uint4(hp[4], hp[5], hp[6], hp[7]);
  *(uint4*)&Al[tokl][dg * 16] = make_uint4(lp[0], lp[1], lp[2], lp[3]);
  *(uint4*)&Al[tokl][dg * 16 + 8] = make_uint4(lp[4], lp[5], lp[6], lp[7]);
  __syncthreads();
  const int wave = t >> 6, lane = t & 63, l16 = lane & 15, quad = lane >> 4;
  f32x4_t acc[4][3] = {};
#pragma unroll
  for (int ks = 0; ks < 2; ++ks) {
    int ko = ks * 32 + quad * 8;
    bf16x8_t bh0[3], bl0[3];
#pragma unroll
    for (int nt = 0; nt < 3; ++nt) {
      int col = wave * 48 + nt * 16 + l16;
      bh0[nt] = *(const bf16x8_t*)(wh + col * 64 + ko);
      bl0[nt] = *(const bf16x8_t*)(wl + col * 64 + ko);
    }
#pragma unroll
    for (int mt = 0; mt < 4; ++mt) {
      bf16x8_t ah = *(const bf16x8_t*)&Ah[mt * 16 + l16][ko];
      bf16x8_t al = *(const bf16x8_t*)&Al[mt * 16 + l16][ko];
#pragma unroll
      for (int nt = 0; nt < 3; ++nt) {
        acc[mt][nt] = MFMA16(ah, bh0[nt], acc[mt][nt]);
        acc[mt][nt] = MFMA16(ah, bl0[nt], acc[mt][nt]);
        acc[mt][nt] = MFMA16(al, bh0[nt], acc[mt][nt]);
      }
    }
  }
#pragma unroll
  for (int nt = 0; nt < 3; ++nt) {
    int col = wave * 48 + nt * 16 + l16;
    float bqv = bq[col];
    if (col < 64) bqv *= 0.125f;
#pragma unroll
    for (int mt = 0; mt < 4; ++mt) {
#pragma unroll
      for (int r = 0; r < 4; ++r) {
        int tok = tok0 + mt * 16 + quad * 4 + r;
        float val = acc[mt][nt][r] + bqv;
        unsigned short hh, ll;
        cvt1(val, hh, ll);
        if (col < 64) {
          size_t o = ((size_t)pair * 1024 + tok) * 64 + col;
          qh[o] = hh; ql[o] = ll;
        } else if (col < 128) {
          size_t o = ((size_t)pair * 1024 + tok) * 64 + (col - 64);
          kh[o] = hh; kl[o] = ll;
        } else {
          size_t o = ((size_t)pair * 64 + (col - 128)) * 1024 + tok;
          vth[o] = hh; vtl[o] = ll;
        }
      }
    }
  }
}

// ---------------- coarse fused attention (score path, bit-identical) -------
// Q panel in registers; K (pass1) / K+V (pass2) register-prefetched.
__global__ __launch_bounds__(256, 2) void k_attn_coarse(
    const unsigned short* __restrict__ qh, const unsigned short* __restrict__ ql,
    const unsigned short* __restrict__ kh, const unsigned short* __restrict__ kl,
    const unsigned short* __restrict__ vth, const unsigned short* __restrict__ vtl,
    float* __restrict__ score, unsigned* __restrict__ outc) {
  __shared__ __align__(16) unsigned short Kb[2][64][72];
  __shared__ __align__(16) unsigned short Vb[2][64][72];
  __shared__ __align__(16) unsigned short Pb[2][64][72];
  __shared__ float mlW[4][2][64];
  __shared__ float mC[64], lC[64];
  __shared__ float colsum[1024];
  const int t = threadIdx.x;
  const int q0 = blockIdx.x * 64;
  const int pair = blockIdx.y;
  const int wave = t >> 6, lane = t & 63;
  const int l16 = lane & 15, quad = lane >> 4;
  const int wm = wave * 16;
  const int sr = t >> 3, skc = (t & 7) * 8;

  const size_t qbase = ((size_t)pair * 1024 + q0) * 64;
  // Q fragments in registers: B-operand rows nt*16+l16, k-slice ks*32+quad*8
  bf16x8_t qh_r[2][4], ql_r[2][4];
#pragma unroll
  for (int ks = 0; ks < 2; ++ks)
#pragma unroll
    for (int nt = 0; nt < 4; ++nt) {
      int row = nt * 16 + l16, col = ks * 32 + quad * 8;
      qh_r[ks][nt] = *(const bf16x8_t*)(qh + qbase + (size_t)row * 64 + col);
      ql_r[ks][nt] = *(const bf16x8_t*)(ql + qbase + (size_t)row * 64 + col);
    }
#pragma unroll
  for (int i = 0; i < 4; ++i) colsum[t + i * 256] = 0.f;

  const size_t kmbase = (size_t)pair * 1024 * 64;
  const size_t vbase = (size_t)pair * 64 * 1024;

  // prologue prefetch: pass-1 chunk 0
  bf16x8_t pk0[2], pk1[2];
#pragma unroll
  for (int i = 0; i < 2; ++i) {
    int r = sr + i * 32;
    pk0[i] = *(const bf16x8_t*)(kh + kmbase + (size_t)r * 64 + skc);
    pk1[i] = *(const bf16x8_t*)(kl + kmbase + (size_t)r * 64 + skc);
  }

  // ---- pass 1: online (m,l), numerics identical ----
  float mrun[4] = {-1e30f, -1e30f, -1e30f, -1e30f};
  float lrun[4] = {0.f, 0.f, 0.f, 0.f};
  for (int kb = 0; kb < 1024; kb += 64) {
    __syncthreads();
#pragma unroll
    for (int i = 0; i < 2; ++i) {
      int r = sr + i * 32;
      *(bf16x8_t*)&Kb[0][r][skc] = pk0[i];
      *(bf16x8_t*)&Kb[1][r][skc] = pk1[i];
    }
    if (kb + 64 < 1024) {  // prefetch next chunk
#pragma unroll
      for (int i = 0; i < 2; ++i) {
        int r = sr + i * 32;
        pk0[i] = *(const bf16x8_t*)(kh + kmbase + (size_t)(kb + 64 + r) * 64 + skc);
        pk1[i] = *(const bf16x8_t*)(kl + kmbase + (size_t)(kb + 64 + r) * 64 + skc);
      }
    }
    __syncthreads();
    f32x4_t acc[4] = {};
    mfma_chunk_regB(Kb[0], Kb[1], qh_r, ql_r, acc, wm, lane);
#pragma unroll
    for (int nt = 0; nt < 4; ++nt) {
      float m0 = fmaxf(fmaxf(acc[nt][0], acc[nt][1]), fmaxf(acc[nt][2], acc[nt][3]));
      m0 = fmaxf(m0, __shfl_xor(m0, 16));
      m0 = fmaxf(m0, __shfl_xor(m0, 32));
      float mn = fmaxf(mrun[nt], m0);
      float s0 = __expf(acc[nt][0] - mn) + __expf(acc[nt][1] - mn) +
                 __expf(acc[nt][2] - mn) + __expf(acc[nt][3] - mn);
      s0 += __shfl_xor(s0, 16);
      s0 += __shfl_xor(s0, 32);
      lrun[nt] = lrun[nt] * __expf(mrun[nt] - mn) + s0;
      mrun[nt] = mn;
    }
  }
  // issue pass-2 chunk-0 prefetch (K and V) before the m/l merge section
  bf16x8_t pv0[2], pv1[2];
#pragma unroll
  for (int i = 0; i < 2; ++i) {
    int r = sr + i * 32;
    pk0[i] = *(const bf16x8_t*)(kh + kmbase + (size_t)r * 64 + skc);
    pk1[i] = *(const bf16x8_t*)(kl + kmbase + (size_t)r * 64 + skc);
    pv0[i] = *(const bf16x8_t*)(vth + vbase + (size_t)r * 1024 + skc);
    pv1[i] = *(const bf16x8_t*)(vtl + vbase + (size_t)r * 1024 + skc);
  }
  __syncthreads();
  if (quad == 0) {
#pragma unroll
    for (int nt = 0; nt < 4; ++nt) {
      mlW[wave][0][nt * 16 + l16] = mrun[nt];
      mlW[wave][1][nt * 16 + l16] = lrun[nt];
    }
  }
  __syncthreads();
  if (t < 64) {
    float m0 = mlW[0][0][t], m1 = mlW[1][0][t], m2 = mlW[2][0][t], m3 = mlW[3][0][t];
    float mm = fmaxf(fmaxf(m0, m1), fmaxf(m2, m3));
    float ll = mlW[0][1][t] * __expf(m0 - mm) + mlW[1][1][t] * __expf(m1 - mm) +
               mlW[2][1][t] * __expf(m2 - mm) + mlW[3][1][t] * __expf(m3 - mm);
    mC[t] = mm;
    lC[t] = 1.0f / ll;
  }
  __syncthreads();
  float mq[4], il[4];
#pragma unroll
  for (int nt = 0; nt < 4; ++nt) {
    mq[nt] = mC[nt * 16 + l16];
    il[nt] = lC[nt * 16 + l16];
  }

  // ---- pass 2: recompute, final P, colsum, PV. 3 barriers/chunk ----
  f32x4_t accO[4] = {};
  for (int kb = 0; kb < 1024; kb += 64) {
    __syncthreads();  // prev PV done reading Pb/Vb
#pragma unroll
    for (int i = 0; i < 2; ++i) {
      int r = sr + i * 32;
      *(bf16x8_t*)&Kb[0][r][skc] = pk0[i];
      *(bf16x8_t*)&Kb[1][r][skc] = pk1[i];
      *(bf16x8_t*)&Vb[0][r][skc] = pv0[i];
      *(bf16x8_t*)&Vb[1][r][skc] = pv1[i];
    }
    if (kb + 64 < 1024) {  // prefetch next chunk
#pragma unroll
      for (int i = 0; i < 2; ++i) {
        int r = sr + i * 32;
        pk0[i] = *(const bf16x8_t*)(kh + kmbase + (size_t)(kb + 64 + r) * 64 + skc);
        pk1[i] = *(const bf16x8_t*)(kl + kmbase + (size_t)(kb + 64 + r) * 64 + skc);
        pv0[i] = *(const bf16x8_t*)(vth + vbase + (size_t)r * 1024 + kb + 64 + skc);
        pv1[i] = *(const bf16x8_t*)(vtl + vbase + (size_t)r * 1024 + kb + 64 + skc);
      }
    }
    __syncthreads();
    f32x4_t acc[4] = {};
    mfma_chunk_regB(Kb[0], Kb[1], qh_r, ql_r, acc, wm, lane);
    float P[4][4];
#pragma unroll
    for (int nt = 0; nt < 4; ++nt)
#pragma unroll
      for (int r = 0; r < 4; ++r) P[nt][r] = __expf(acc[nt][r] - mq[nt]) * il[nt];
#pragma unroll
    for (int r = 0; r < 4; ++r) {
      float cs = P[0][r] + P[1][r] + P[2][r] + P[3][r];
      cs += __shfl_xor(cs, 1);
      cs += __shfl_xor(cs, 2);
      cs += __shfl_xor(cs, 4);
      cs += __shfl_xor(cs, 8);
      if (l16 == 0) colsum[kb + wm + quad * 4 + r] += cs;
    }
#pragma unroll
    for (int nt = 0; nt < 4; ++nt) {
      unsigned h01, l01, h23, l23;
      cvt2(P[nt][0], P[nt][1], h01, l01);
      cvt2(P[nt][2], P[nt][3], h23, l23);
      *(uint2*)&Pb[0][nt * 16 + l16][wm + quad * 4] = make_uint2(h01, h23);
      *(uint2*)&Pb[1][nt * 16 + l16][wm + quad * 4] = make_uint2(l01, l23);
    }
    __syncthreads();  // Pb visible
    mfma_chunk(Pb[0], Pb[1], Vb[0], Vb[1], accO, wm, lane);
  }
  __syncthreads();

#pragma unroll
  for (int i = 0; i < 4; ++i)
    atomicAdd(&score[pair * 1024 + t + i * 256], colsum[t + i * 256]);
  float (*Tr)[68] = reinterpret_cast<float(*)[68]>(&Pb[0][0][0]);
#pragma unroll
  for (int nt = 0; nt < 4; ++nt)
#pragma unroll
    for (int r = 0; r < 4; ++r)
      Tr[nt * 16 + l16][wm + quad * 4 + r] = accO[nt][r];
  __syncthreads();
  const int b = pair >> 2, h = pair & 3;
#pragma unroll
  for (int i = 0; i < 16; ++i) {
    int e = t + i * 256;
    int d = e >> 6, ql_ = e & 63;
    int pix = q0 + ql_;
    int iy = (pix >> 5) + 1, ix = (pix & 31) + 1;
    outc[((size_t)(b * 256 + h * 64 + d)) * 1156 + iy * 34 + ix] = cvtpack(Tr[d][ql_]);
  }
}

// ---------------- fine fused attention: single-pass online flash -----------
// Q panel in registers; K+V register-prefetched.
__global__ __launch_bounds__(256, 2) void k_attn_fine(
    const unsigned short* __restrict__ qh, const unsigned short* __restrict__ ql,
    const unsigned short* __restrict__ kh, const unsigned short* __restrict__ kl,
    const unsigned short* __restrict__ vth, const unsigned short* __restrict__ vtl,
    float* __restrict__ outf) {
  __shared__ __align__(16) unsigned short Kb[2][64][72];
  __shared__ __align__(16) unsigned short Vb[2][64][72];
  __shared__ __align__(16) unsigned short Pb[2][64][72];
  __shared__ float m_run[64], l_run[64], alphaS[64];
  __shared__ float mWc[4][64], sWc[4][64];
  const int t = threadIdx.x;
  const int q0 = blockIdx.x * 64;
  const int pair = blockIdx.y;
  const int wave = t >> 6, lane = t & 63;
  const int l16 = lane & 15, quad = lane >> 4;
  const int wm = wave * 16;
  const int sr = t >> 3, skc = (t & 7) * 8;

  const size_t qbase = ((size_t)pair * 1024 + q0) * 64;
  bf16x8_t qh_r[2][4], ql_r[2][4];
#pragma unroll
  for (int ks = 0; ks < 2; ++ks)
#pragma unroll
    for (int nt = 0; nt < 4; ++nt) {
      int row = nt * 16 + l16, col = ks * 32 + quad * 8;
      qh_r[ks][nt] = *(const bf16x8_t*)(qh + qbase + (size_t)row * 64 + col);
      ql_r[ks][nt] = *(const bf16x8_t*)(ql + qbase + (size_t)row * 64 + col);
    }
  if (t < 64) { m_run[t] = -1e30f; l_run[t] = 0.f; }

  const size_t kmbase = (size_t)pair * 1024 * 64;
  const size_t vbase = (size_t)pair * 64 * 1024;

  // prologue prefetch: chunk 0
  bf16x8_t pk0[2], pk1[2], pv0[2], pv1[2];
#pragma unroll
  for (int i = 0; i < 2; ++i) {
    int r = sr + i * 32;
    pk0[i] = *(const bf16x8_t*)(kh + kmbase + (size_t)r * 64 + skc);
    pk1[i] = *(const bf16x8_t*)(kl + kmbase + (size_t)r * 64 + skc);
    pv0[i] = *(const bf16x8_t*)(vth + vbase + (size_t)r * 1024 + skc);
    pv1[i] = *(const bf16x8_t*)(vtl + vbase + (size_t)r * 1024 + skc);
  }

  f32x4_t accO[4] = {};
  for (int kb = 0; kb < 1024; kb += 64) {
    __syncthreads();  // prev PV done reading Pb/Vb; m/l arrays consumed
#pragma unroll
    for (int i = 0; i < 2; ++i) {
      int r = sr + i * 32;
      *(bf16x8_t*)&Kb[0][r][skc] = pk0[i];
      *(bf16x8_t*)&Kb[1][r][skc] = pk1[i];
      *(bf16x8_t*)&Vb[0][r][skc] = pv0[i];
      *(bf16x8_t*)&Vb[1][r][skc] = pv1[i];
    }
    if (kb + 64 < 1024) {  // prefetch next chunk
#pragma unroll
      for (int i = 0; i < 2; ++i) {
        int r = sr + i * 32;
        pk0[i] = *(const bf16x8_t*)(kh + kmbase + (size_t)(kb + 64 + r) * 64 + skc);
        pk1[i] = *(const bf16x8_t*)(kl + kmbase + (size_t)(kb + 64 + r) * 64 + skc);
        pv0[i] = *(const bf16x8_t*)(vth + vbase + (size_t)r * 1024 + kb + 64 + skc);
        pv1[i] = *(const bf16x8_t*)(vtl + vbase + (size_t)r * 1024 + kb + 64 + skc);
      }
    }
    __syncthreads();
    f32x4_t acc[4] = {};
    mfma_chunk_regB(Kb[0], Kb[1], qh_r, ql_r, acc, wm, lane);  // S^T tile
    // per-wave k-max per q
#pragma unroll
    for (int nt = 0; nt < 4; ++nt) {
      float m0 = fmaxf(fmaxf(acc[nt][0], acc[nt][1]), fmaxf(acc[nt][2], acc[nt][3]));
      m0 = fmaxf(m0, __shfl_xor(m0, 16));
      m0 = fmaxf(m0, __shfl_xor(m0, 32));
      if (quad == 0) mWc[wave][nt * 16 + l16] = m0;
    }
    __syncthreads();
    if (t < 64) {
      float mn = fmaxf(fmaxf(fmaxf(mWc[0][t], mWc[1][t]), fmaxf(mWc[2][t], mWc[3][t])),
                       m_run[t]);
      alphaS[t] = __expf(m_run[t] - mn);
      m_run[t] = mn;
    }
    __syncthreads();
    // P = exp(s - m_new); write Pb; per-wave partial l sums; rescale accO
    float P[4][4];
#pragma unroll
    for (int nt = 0; nt < 4; ++nt) {
      float mn = m_run[nt * 16 + l16];
#pragma unroll
      for (int r = 0; r < 4; ++r) P[nt][r] = __expf(acc[nt][r] - mn);
      float s0 = P[nt][0] + P[nt][1] + P[nt][2] + P[nt][3];
      s0 += __shfl_xor(s0, 16);
      s0 += __shfl_xor(s0, 32);
      if (quad == 0) sWc[wave][nt * 16 + l16] = s0;
      unsigned h01, l01, h23, l23;
      cvt2(P[nt][0], P[nt][1], h01, l01);
      cvt2(P[nt][2], P[nt][3], h23, l23);
      *(uint2*)&Pb[0][nt * 16 + l16][wm + quad * 4] = make_uint2(h01, h23);
      *(uint2*)&Pb[1][nt * 16 + l16][wm + quad * 4] = make_uint2(l01, l23);
    }
#pragma unroll
    for (int r = 0; r < 4; ++r) {
      float a = alphaS[wm + quad * 4 + r];
#pragma unroll
      for (int nt = 0; nt < 4; ++nt) accO[nt][r] *= a;
    }
    __syncthreads();  // Pb + sWc visible
    if (t < 64)
      l_run[t] = l_run[t] * alphaS[t] + (sWc[0][t] + sWc[1][t] + sWc[2][t] + sWc[3][t]);
    mfma_chunk(Pb[0], Pb[1], Vb[0], Vb[1], accO, wm, lane);  // O += P~ @ V
  }
  __syncthreads();
#pragma unroll
  for (int r = 0; r < 4; ++r) {
    float invl = 1.0f / l_run[wm + quad * 4 + r];
    int qm = q0 + wm + quad * 4 + r;
#pragma unroll
    for (int nt = 0; nt < 4; ++nt)
      outf[((size_t)pair * 1024 + qm) * 64 + nt * 16 + l16] = accO[nt][r] * invl;
  }
}

// ---------------- per-pair top-256 via bitonic sort ------------------------
__global__ __launch_bounds__(256) void k_topk(
    const float* __restrict__ score, int* __restrict__ idx) {
  __shared__ unsigned long long key[1024];
  const int pair = blockIdx.x;
  const int t = threadIdx.x;
#pragma unroll
  for (int j = 0; j < 4; ++j) {
    int i = t + j * 256;
    unsigned u = __float_as_uint(score[pair * 1024 + i]);
    u = u ^ ((u & 0x80000000u) ? 0xFFFFFFFFu : 0x80000000u);
    u = ~u;
    key[i] = ((unsigned long long)u << 32) | (unsigned)i;
  }
  __syncthreads();
  for (int k = 2; k <= 1024; k <<= 1) {
    for (int j = k >> 1; j > 0; j >>= 1) {
      for (int w = 0; w < 4; ++w) {
        int i = t + w * 256;
        int l = i ^ j;
        if (l > i) {
          bool up = ((i & k) == 0);
          unsigned long long a = key[i], b = key[l];
          if ((a > b) == up) { key[i] = b; key[l] = a; }
        }
      }
      __syncthreads();
    }
  }
  idx[pair * 256 + t] = (int)(key[t] & 0xFFFFFFFFu);
}

// ---------------- convT: 64oc x 128pix tile, 4 classes, pipelined ----------
__global__ __launch_bounds__(256) void k_convT_mfma(
    const unsigned* __restrict__ inp, const unsigned short* __restrict__ wth,
    const unsigned short* __restrict__ wtl, const float* __restrict__ bias,
    float* __restrict__ out) {
  __shared__ unsigned short Ah[64][72], Al[64][72];
  __shared__ unsigned short Bh[128][72], Bl[128][72];
  const int t = threadIdx.x;
  const int pix0 = blockIdx.x * 128;
  const int oc0 = blockIdx.y * 64;
  const int cls = blockIdx.z;
  const int ry = cls >> 1, rx = cls & 1;
  const int b = pix0 >> 10;
  const int wave = t >> 6, lane = t & 63;
  const int l16 = lane & 15, quad = lane >> 4;
  const int wm = (wave & 1) * 32, wn = (wave >> 1) * 64;
  const int pl = t & 127, icg = t >> 7;
  const int remg = (pix0 + pl) & 1023;
  const int tyy = remg >> 5, txx = remg & 31;
  const int ar = t >> 2, ac = (t & 3) * 16;
  const size_t wbase = ((size_t)cls * 256 + oc0 + ar) * 1024 + ac;
  f32x4_t acc[2][4] = {};
  bf16x8_t a0, a1, a2, a3;
  unsigned u[32];
  // prologue: chunk kb=0 (tap 0 -> tk=0, txi=0; ic0=0)
  {
    const int iy = tyy + ry + 1, ix = txx + rx + 1;
    const unsigned* p = inp + (size_t)(b * 256 + icg * 32) * 1156 + iy * 34 + ix;
#pragma unroll
    for (int j = 0; j < 32; ++j) u[j] = p[(size_t)j * 1156];
    a0 = *(const bf16x8_t*)(wth + wbase);
    a1 = *(const bf16x8_t*)(wth + wbase + 8);
    a2 = *(const bf16x8_t*)(wtl + wbase);
    a3 = *(const bf16x8_t*)(wtl + wbase + 8);
  }
  for (int kb = 0; kb < 1024; kb += 64) {
    unsigned hp[16], lpk[16];
#pragma unroll
    for (int j = 0; j < 16; ++j) {
      hp[j] = pk_h(u[2 * j], u[2 * j + 1]);
      lpk[j] = pk_l(u[2 * j], u[2 * j + 1]);
    }
    __syncthreads();
    *(bf16x8_t*)&Ah[ar][ac] = a0;
    *(bf16x8_t*)&Ah[ar][ac + 8] = a1;
    *(bf16x8_t*)&Al[ar][ac] = a2;
    *(bf16x8_t*)&Al[ar][ac + 8] = a3;
    {
      int kc = icg * 32;
      *(uint4*)&Bh[pl][kc] = make_uint4(hp[0], hp[1], hp[2], hp[3]);
      *(uint4*)&Bh[pl][kc + 8] = make_uint4(hp[4], hp[5], hp[6], hp[7]);
      *(uint4*)&Bh[pl][kc + 16] = make_uint4(hp[8], hp[9], hp[10], hp[11]);
      *(uint4*)&Bh[pl][kc + 24] = make_uint4(hp[12], hp[13], hp[14], hp[15]);
      *(uint4*)&Bl[pl][kc] = make_uint4(lpk[0], lpk[1], lpk[2], lpk[3]);
      *(uint4*)&Bl[pl][kc + 8] = make_uint4(lpk[4], lpk[5], lpk[6], lpk[7]);
      *(uint4*)&Bl[pl][kc + 16] = make_uint4(lpk[8], lpk[9], lpk[10], lpk[11]);
      *(uint4*)&Bl[pl][kc + 24] = make_uint4(lpk[12], lpk[13], lpk[14], lpk[15]);
    }
    if (kb + 64 < 1024) {  // prefetch next chunk
      const int kn = kb + 64;
      const int tap = kn >> 8, ic0 = kn & 255;
      const int tk = tap >> 1, txi = tap & 1;
      const int iy = tyy + ry + 1 - tk, ix = txx + rx + 1 - txi;
      const unsigned* p = inp + (size_t)(b * 256 + ic0 + icg * 32) * 1156 + iy * 34 + ix;
#pragma unroll
      for (int j = 0; j < 32; ++j) u[j] = p[(size_t)j * 1156];
      a0 = *(const bf16x8_t*)(wth + wbase + kn);
      a1 = *(const bf16x8_t*)(wth + wbase + kn + 8);
      a2 = *(const bf16x8_t*)(wtl + wbase + kn);
      a3 = *(const bf16x8_t*)(wtl + wbase + kn + 8);
    }
    __syncthreads();
    mfma_tile2x4(Ah, Al, Bh, Bl, acc, wm, wn, lane);
  }
#pragma unroll
  for (int mt = 0; mt < 2; ++mt)
#pragma unroll
    for (int r = 0; r < 4; ++r) {
      int oc = oc0 + wm + mt * 16 + quad * 4 + r;
      float bvs = bias[oc];
#pragma unroll
      for (int nt = 0; nt < 4; ++nt) {
        int pix = pix0 + wn + nt * 16 + l16;
        int rem2 = pix & 1023;
        int y = (rem2 >> 5) * 2 + ry, xx = (rem2 & 31) * 2 + rx;
        out[((size_t)(b * 256 + oc) * 64 + y) * 64 + xx] = acc[mt][nt][r] + bvs;
      }
    }
}

// ---------------- scatter fine outputs into y ------------------------------
__global__ __launch_bounds__(256) void k_scatter(
    const float* __restrict__ outf, const int* __restrict__ idx,
    float* __restrict__ y) {
  int g = blockIdx.x * 256 + threadIdx.x;
  int pair = g >> 16;
  int rem = g & 65535;
  int tok = rem >> 6, d = rem & 63;
  int b = pair >> 2, h = pair & 3;
  int pp = idx[pair * 256 + (tok >> 2)];
  int py = (tok >> 1) & 1, px = tok & 1;
  int ry = (pp >> 5) * 2 + py, rx = (pp & 31) * 2 + px;
  y[((size_t)(b * 256 + h * 64 + d) * 64 + ry) * 64 + rx] += outf[g];
}

// ---------------- depthwise 3x3 + BN + relu6 -> packed yd ------------------
__global__ __launch_bounds__(256) void k_dwconv(
    const float* __restrict__ y, const float* __restrict__ wdw,
    const float* __restrict__ g, const float* __restrict__ bb,
    const float* __restrict__ m, const float* __restrict__ vv,
    unsigned* __restrict__ ydhl) {
  int gi = blockIdx.x * 256 + threadIdx.x;
  int x = gi & 63, yy = (gi >> 6) & 63, ch = (gi >> 12) & 255, b = gi >> 20;
  const float* plane = y + (size_t)(b * 256 + ch) * 4096;
  const float* wc = wdw + ch * 9;
  float s = 0.f;
#pragma unroll
  for (int ky = 0; ky < 3; ++ky) {
    int iy = yy + ky - 1;
    if (iy < 0 || iy >= 64) continue;
#pragma unroll
    for (int kx = 0; kx < 3; ++kx) {
      int ix = x + kx - 1;
      if (ix < 0 || ix >= 64) continue;
      s = fmaf(plane[iy * 64 + ix], wc[ky * 3 + kx], s);
    }
  }
  float sc = g[ch] * rsqrtf(vv[ch] + EPS_);
  float val = s * sc + (bb[ch] - m[ch] * sc);
  ydhl[gi] = cvtpack(fminf(fmaxf(val, 0.f), 6.f));
}

// ---------------- pointwise 1x1 + BN + relu6, 64oc x 128pix, pipelined -----
__global__ __launch_bounds__(256) void k_pw_mfma(
    const unsigned* __restrict__ ydhl, const unsigned short* __restrict__ wh,
    const unsigned short* __restrict__ wl, const float* __restrict__ g,
    const float* __restrict__ bb, const float* __restrict__ m,
    const float* __restrict__ vv, float* __restrict__ out) {
  __shared__ unsigned short Ah[64][72], Al[64][72];
  __shared__ unsigned short Bh[128][72], Bl[128][72];
  const int t = threadIdx.x;
  const int pix0 = blockIdx.x * 128;
  const int oc0 = blockIdx.y * 64;
  const int b = pix0 >> 12, pos0 = pix0 & 4095;
  const int wave = t >> 6, lane = t & 63;
  const int l16 = lane & 15, quad = lane >> 4;
  const int wm = (wave & 1) * 32, wn = (wave >> 1) * 64;
  const int pl = t & 127, icg = t >> 7;
  const int ar = t >> 2, ac = (t & 3) * 16;
  f32x4_t acc[2][4] = {};
  bf16x8_t a0, a1, a2, a3;
  unsigned u[32];
  // prologue: chunk kb=0
  {
    const unsigned* p = ydhl + (size_t)(b * 256 + icg * 32) * 4096 + pos0 + pl;
#pragma unroll
    for (int j = 0; j < 32; ++j) u[j] = p[(size_t)j * 4096];
    a0 = *(const bf16x8_t*)(wh + (size_t)(oc0 + ar) * 256 + ac);
    a1 = *(const bf16x8_t*)(wh + (size_t)(oc0 + ar) * 256 + ac + 8);
    a2 = *(const bf16x8_t*)(wl + (size_t)(oc0 + ar) * 256 + ac);
    a3 = *(const bf16x8_t*)(wl + (size_t)(oc0 + ar) * 256 + ac + 8);
  }
  for (int kb = 0; kb < 256; kb += 64) {
    unsigned hp[16], lpk[16];
#pragma unroll
    for (int j = 0; j < 16; ++j) {
      hp[j] = pk_h(u[2 * j], u[2 * j + 1]);
      lpk[j] = pk_l(u[2 * j], u[2 * j + 1]);
    }
    __syncthreads();
    *(bf16x8_t*)&Ah[ar][ac] = a0;
    *(bf16x8_t*)&Ah[ar][ac + 8] = a1;
    *(bf16x8_t*)&Al[ar][ac] = a2;
    *(bf16x8_t*)&Al[ar][ac + 8] = a3;
    {
      int kc = icg * 32;
      *(uint4*)&Bh[pl][kc] = make_uint4(hp[0], hp[1], hp[2], hp[3]);
      *(uint4*)&Bh[pl][kc + 8] = make_uint4(hp[4], hp[5], hp[6], hp[7]);
      *(uint4*)&Bh[pl][kc + 16] = make_uint4(hp[8], hp[9], hp[10], hp[11]);
      *(uint4*)&Bh[pl][kc + 24] = make_uint4(hp[12], hp[13], hp[14], hp[15]);
      *(uint4*)&Bl[pl][kc] = make_uint4(lpk[0], lpk[1], lpk[2], lpk[3]);
      *(uint4*)&Bl[pl][kc + 8] = make_uint4(lpk[4], lpk[5], lpk[6], lpk[7]);
      *(uint4*)&Bl[pl][kc + 16] = make_uint4(lpk[8], lpk[9], lpk[10], lpk[11]);
      *(uint4*)&Bl[pl][kc + 24] = make_uint4(lpk[12], lpk[13], lpk[14], lpk[15]);
    }
    if (kb + 64 < 256) {  // prefetch next chunk
      const int kn = kb + 64;
      const unsigned* p = ydhl + (size_t)(b * 256 + kn + icg * 32) * 4096 + pos0 + pl;
#pragma unroll
      for (int j = 0; j < 32; ++j) u[j] = p[(size_t)j * 4096];
      a0 = *(const bf16x8_t*)(wh + (size_t)(oc0 + ar) * 256 + kn + ac);
      a1 = *(const bf16x8_t*)(wh + (size_t)(oc0 + ar) * 256 + kn + ac + 8);
      a2 = *(const bf16x8_t*)(wl + (size_t)(oc0 + ar) * 256 + kn + ac);
      a3 = *(const bf16x8_t*)(wl + (size_t)(oc0 + ar) * 256 + kn + ac + 8);
    }
    __syncthreads();
    mfma_tile2x4(Ah, Al, Bh, Bl, acc, wm, wn, lane);
  }
#pragma unroll
  for (int mt = 0; mt < 2; ++mt)
#pragma unroll
    for (int r = 0; r < 4; ++r) {
      int oc = oc0 + wm + mt * 16 + quad * 4 + r;
      float sc = g[oc] * rsqrtf(vv[oc] + EPS_);
      float off = bb[oc] - m[oc] * sc;
#pragma unroll
      for (int nt = 0; nt < 4; ++nt) {
        int pix = pos0 + wn + nt * 16 + l16;
        float val = fminf(fmaxf(acc[mt][nt][r] * sc + off, 0.f), 6.f);
        out[(size_t)(b * 256 + oc) * 4096 + pix] = val;
      }
    }
}

// ---------------------------------------------------------------------------
extern "C" void kernel_launch(void* const* d_in, const int* in_sizes, int n_in,
                              void* d_out, int out_size, void* d_ws, size_t ws_size,
                              hipStream_t stream) {
  (void)in_sizes; (void)n_in; (void)out_size; (void)ws_size;
  const float* x       = (const float*)d_in[0];
  const float* w_down  = (const float*)d_in[1];
  const float* b_down  = (const float*)d_in[2];
  const float* w_qkv_c = (const float*)d_in[3];
  const float* b_qkv_c = (const float*)d_in[4];
  const float* w_up    = (const float*)d_in[5];
  const float* b_up    = (const float*)d_in[6];
  const float* w_qkv_f = (const float*)d_in[7];
  const float* b_qkv_f = (const float*)d_in[8];
  const float* w_dw    = (const float*)d_in[9];
  const float* bn_dw_g = (const float*)d_in[10];
  const float* bn_dw_b = (const float*)d_in[11];
  const float* bn_dw_m = (const float*)d_in[12];
  const float* bn_dw_v = (const float*)d_in[13];
  const float* w_pw    = (const float*)d_in[14];
  const float* bn_pw_g = (const float*)d_in[15];
  const float* bn_pw_b = (const float*)d_in[16];
  const float* bn_pw_m = (const float*)d_in[17];
  const float* bn_pw_v = (const float*)d_in[18];

  float* ws = (float*)d_ws;  // offsets in 4-byte units (round 6/8 layout)
  unsigned*       xphl   = (unsigned*)ws;                   // 9,191,424 u
  unsigned*       ydhl   = (unsigned*)ws;                   // alias (xphl dead by then)
  unsigned short* qh     = (unsigned short*)(ws + 33554432);
  unsigned short* ql     = (unsigned short*)(ws + 34603008);
  unsigned short* kh     = (unsigned short*)(ws + 35651584);
  unsigned short* kl     = (unsigned short*)(ws + 36700160);
  unsigned short* vth    = (unsigned short*)(ws + 37748736);
  unsigned short* vtl    = (unsigned short*)(ws + 38797312);
  unsigned*       xdhl   = (unsigned*)(ws + 39845888);      // 2,097,152 u
  unsigned*       outcphl= (unsigned*)(ws + 41943040);      // 2,367,488 u
  float*          coarse = ws + 44310528;                   // 8,388,608 f
  float*          outf   = ws + 52699136;                   // 2,097,152 f
  float*          score  = ws + 54796288;                   // 32,768 f
  unsigned short* wdh    = (unsigned short*)(ws + 54829056);
  unsigned short* wdl    = (unsigned short*)(ws + 55353344);
  unsigned short* wt_hi  = (unsigned short*)(ws + 55877632);
  unsigned short* wt_lo  = (unsigned short*)(ws + 56401920);
  unsigned short* wpw_hi = (unsigned short*)(ws + 56926208);
  unsigned short* wpw_lo = (unsigned short*)(ws + 56958976);
  unsigned short* wqh_c  = (unsigned short*)(ws + 56991744);
  unsigned short* wql_c  = (unsigned short*)(ws + 56997888);
  unsigned short* wqh_f  = (unsigned short*)(ws + 57004032);
  unsigned short* wql_f  = (unsigned short*)(ws + 57010176);
  int*            idx    = (int*)(ws + 57016320);           // 8,192 int

  hipMemsetAsync(score, 0, 32768 * sizeof(float), stream);
  hipMemsetAsync(outcphl, 0, (size_t)2367488 * sizeof(unsigned), stream);
  k_pad_x<<<2048, 256, 0, stream>>>(x, xphl);
  k_cvt_wdown<<<4096, 256, 0, stream>>>(w_down, wdh, wdl);
  k_cvt_wqkv<<<48, 256, 0, stream>>>(w_qkv_c, wqh_c, wql_c);
  k_cvt_wqkv<<<48, 256, 0, stream>>>(w_qkv_f, wqh_f, wql_f);
  k_cvt_wup<<<4096, 256, 0, stream>>>(w_up, wt_hi, wt_lo);
  k_cvt_wpw<<<256, 256, 0, stream>>>(w_pw, wpw_hi, wpw_lo);

  k_conv_down_mfma<<<dim3(128, 4), 256, 0, stream>>>(xphl, wdh, wdl, b_down, xdhl);
  k_qkv_mfma<0><<<dim3(16, 32), 256, 0, stream>>>(xdhl, nullptr, wqh_c, wql_c, b_qkv_c,
                                                  nullptr, qh, ql, kh, kl, vth, vtl);
  k_attn_coarse<<<dim3(16, 32), 256, 0, stream>>>(qh, ql, kh, kl, vth, vtl, score, outcphl);
  k_topk<<<32, 256, 0, stream>>>(score, idx);
  k_convT_mfma<<<dim3(64, 4, 4), 256, 0, stream>>>(outcphl, wt_hi, wt_lo, b_up, coarse);

  k_qkv_mfma<1><<<dim3(16, 32), 256, 0, stream>>>(nullptr, coarse, wqh_f, wql_f, b_qkv_f,
                                                  idx, qh, ql, kh, kl, vth, vtl);
  k_attn_fine<<<dim3(16, 32), 256, 0, stream>>>(qh, ql, kh, kl, vth, vtl, outf);
  k_scatter<<<8192, 256, 0, stream>>>(outf, idx, coarse);
  k_dwconv<<<32768, 256, 0, stream>>>(coarse, w_dw, bn_dw_g, bn_dw_b, bn_dw_m, bn_dw_v, ydhl);
  k_pw_mfma<<<dim3(256, 4), 256, 0, stream>>>(ydhl, wpw_hi, wpw_lo, bn_pw_g, bn_pw_b,
                                              bn_pw_m, bn_pw_v, (float*)d_out);
}

// Round 5
// 575.480 us; speedup vs baseline: 1.0540x; 1.0268x over previous
//
#include <hip/hip_runtime.h>
#include <cstdint>
#include <cstddef>

// ---------------------------------------------------------------------------
// RegionSelectionAttention. Round 14: convT & pw retiled to 128oc x 128pix
// with 4x4 per-wave register blocking (wm/wn in {0,64}). Cuts LDS fragment
// reads per MFMA from 0.5 to 0.33 b128 (LDS-BW-bound per round-4 analysis),
// halves barriers and B global fetch per unit work. LDS 73.7KB -> still
// 2 blocks/CU. conv_down keeps dbuf; attention keeps Q-in-registers.
// Arithmetic order unchanged (bit-identical outputs).
// ---------------------------------------------------------------------------

#define EPS_ 1e-5f

typedef short bf16x8_t __attribute__((ext_vector_type(8)));
typedef float f32x4_t __attribute__((ext_vector_type(4)));
#define MFMA16(a, b, c) __builtin_amdgcn_mfma_f32_16x16x32_bf16(a, b, c, 0, 0, 0)

__device__ __forceinline__ void cvt1(float f, unsigned short& h, unsigned short& l) {
  unsigned u = __float_as_uint(f);
  unsigned r = u + 0x7FFFu + ((u >> 16) & 1u);
  h = (unsigned short)(r >> 16);
  float lo = f - __uint_as_float(r & 0xFFFF0000u);
  l = (unsigned short)(__float_as_uint(lo) >> 16);
}
__device__ __forceinline__ unsigned cvtpack(float f) {
  unsigned short h, l;
  cvt1(f, h, l);
  return (unsigned)h | ((unsigned)l << 16);
}
__device__ __forceinline__ void cvt2(float f0, float f1, unsigned& hpack, unsigned& lpack) {
  unsigned u0 = __float_as_uint(f0), u1 = __float_as_uint(f1);
  unsigned r0 = u0 + 0x7FFFu + ((u0 >> 16) & 1u);
  unsigned r1 = u1 + 0x7FFFu + ((u1 >> 16) & 1u);
  hpack = (r0 >> 16) | (r1 & 0xFFFF0000u);
  float l0 = f0 - __uint_as_float(r0 & 0xFFFF0000u);
  float l1 = f1 - __uint_as_float(r1 & 0xFFFF0000u);
  lpack = (__float_as_uint(l0) >> 16) | (__float_as_uint(l1) & 0xFFFF0000u);
}
__device__ __forceinline__ unsigned pk_h(unsigned a, unsigned b) {
  return (a & 0xFFFFu) | (b << 16);
}
__device__ __forceinline__ unsigned pk_l(unsigned a, unsigned b) {
  return (a >> 16) | (b & 0xFFFF0000u);
}

// ---------------- pad x -> packed xphl[plane][66 rows x stride 68] ---------
__global__ __launch_bounds__(256) void k_pad_x(
    const float* __restrict__ x, unsigned* __restrict__ xphl) {
  const int plane = blockIdx.x;  // 2048
  const float* src = x + (size_t)plane * 4096;
  unsigned* dst = xphl + (size_t)plane * 4488;
  for (int e = threadIdx.x; e < 4356; e += 256) {
    int r = e / 66, cc = e - r * 66;
    float v = 0.f;
    if (r >= 1 && r <= 64 && cc >= 1 && cc <= 64) v = src[(r - 1) * 64 + (cc - 1)];
    dst[r * 68 + cc] = cvtpack(v);
  }
}

// ---------------- weight conversions ---------------------------------------
__global__ __launch_bounds__(256) void k_cvt_wdown(
    const float* __restrict__ w, unsigned short* __restrict__ wh,
    unsigned short* __restrict__ wl) {
  int e = blockIdx.x * 256 + threadIdx.x;  // 1,048,576: [oc][4096]
  cvt1(w[e], wh[e], wl[e]);
}

__global__ __launch_bounds__(256) void k_cvt_wqkv(
    const float* __restrict__ wq, unsigned short* __restrict__ wh,
    unsigned short* __restrict__ wl) {
  int e = blockIdx.x * 256 + threadIdx.x;  // 12288: [col][d]
  int col = e >> 6, d = e & 63;
  float f = wq[d * 192 + col];
  if (col < 64) f *= 0.125f;  // fold attn scale into q (pow2: exact)
  cvt1(f, wh[e], wl[e]);
}

__global__ __launch_bounds__(256) void k_cvt_wup(
    const float* __restrict__ w_up, unsigned short* __restrict__ wth,
    unsigned short* __restrict__ wtl) {
  int e = blockIdx.x * 256 + threadIdx.x;  // 2^20: [class][oc][kp=tap*256+ic]
  int kp = e & 1023, oc = (e >> 10) & 255, c = e >> 18;
  int tap = kp >> 8, ic = kp & 255;
  int tk = tap >> 1, txi = tap & 1;
  int ry = c >> 1, rx = c & 1;
  int ky = (1 - ry) + 2 * tk, kx = (1 - rx) + 2 * txi;
  cvt1(w_up[((size_t)(ic * 256 + oc) * 4 + ky) * 4 + kx], wth[e], wtl[e]);
}

__global__ __launch_bounds__(256) void k_cvt_wpw(
    const float* __restrict__ w, unsigned short* __restrict__ wh,
    unsigned short* __restrict__ wl) {
  int e = blockIdx.x * 256 + threadIdx.x;  // 65536 [oc][ic]
  cvt1(w[e], wh[e], wl[e]);
}

// ====================== MFMA cores =========================================
__device__ __forceinline__ void mfma_chunk(
    const unsigned short (*Ah)[72], const unsigned short (*Al)[72],
    const unsigned short (*Bh)[72], const unsigned short (*Bl)[72],
    f32x4_t (&acc)[4], int wm, int lane) {
  const int l16 = lane & 15, quad = lane >> 4;
#pragma unroll
  for (int ks = 0; ks < 2; ++ks) {
    int ko = ks * 32 + quad * 8;
    bf16x8_t ah = *(const bf16x8_t*)&Ah[wm + l16][ko];
    bf16x8_t al = *(const bf16x8_t*)&Al[wm + l16][ko];
#pragma unroll
    for (int nt = 0; nt < 4; ++nt) {
      bf16x8_t bh = *(const bf16x8_t*)&Bh[nt * 16 + l16][ko];
      bf16x8_t bl = *(const bf16x8_t*)&Bl[nt * 16 + l16][ko];
      acc[nt] = MFMA16(ah, bh, acc[nt]);
      acc[nt] = MFMA16(ah, bl, acc[nt]);
      acc[nt] = MFMA16(al, bh, acc[nt]);
    }
  }
}

// S-stage with the loop-invariant Q panel held in registers (B operand).
__device__ __forceinline__ void mfma_chunk_regB(
    const unsigned short (*Ah)[72], const unsigned short (*Al)[72],
    const bf16x8_t (&bh)[2][4], const bf16x8_t (&bl)[2][4],
    f32x4_t (&acc)[4], int wm, int lane) {
  const int l16 = lane & 15, quad = lane >> 4;
#pragma unroll
  for (int ks = 0; ks < 2; ++ks) {
    int ko = ks * 32 + quad * 8;
    bf16x8_t ah = *(const bf16x8_t*)&Ah[wm + l16][ko];
    bf16x8_t al = *(const bf16x8_t*)&Al[wm + l16][ko];
#pragma unroll
    for (int nt = 0; nt < 4; ++nt) {
      acc[nt] = MFMA16(ah, bh[ks][nt], acc[nt]);
      acc[nt] = MFMA16(ah, bl[ks][nt], acc[nt]);
      acc[nt] = MFMA16(al, bh[ks][nt], acc[nt]);
    }
  }
}

__device__ __forceinline__ void mfma_tile2x2(
    const unsigned short (*Ah)[72], const unsigned short (*Al)[72],
    const unsigned short (*Bh)[72], const unsigned short (*Bl)[72],
    f32x4_t (&acc)[2][2], int wm, int wn, int lane) {
  const int l16 = lane & 15, quad = lane >> 4;
#pragma unroll
  for (int ks = 0; ks < 2; ++ks) {
    int ko = ks * 32 + quad * 8;
    bf16x8_t ah[2], al[2];
#pragma unroll
    for (int mt = 0; mt < 2; ++mt) {
      ah[mt] = *(const bf16x8_t*)&Ah[wm + mt * 16 + l16][ko];
      al[mt] = *(const bf16x8_t*)&Al[wm + mt * 16 + l16][ko];
    }
#pragma unroll
    for (int nt = 0; nt < 2; ++nt) {
      bf16x8_t bh = *(const bf16x8_t*)&Bh[wn + nt * 16 + l16][ko];
      bf16x8_t bl = *(const bf16x8_t*)&Bl[wn + nt * 16 + l16][ko];
#pragma unroll
      for (int mt = 0; mt < 2; ++mt) {
        acc[mt][nt] = MFMA16(ah[mt], bh, acc[mt][nt]);
        acc[mt][nt] = MFMA16(ah[mt], bl, acc[mt][nt]);
        acc[mt][nt] = MFMA16(al[mt], bh, acc[mt][nt]);
      }
    }
  }
}

// 4x4 register-blocked tile: wave covers 64 A-rows x 64 B-rows.
__device__ __forceinline__ void mfma_tile4x4(
    const unsigned short (*Ah)[72], const unsigned short (*Al)[72],
    const unsigned short (*Bh)[72], const unsigned short (*Bl)[72],
    f32x4_t (&acc)[4][4], int wm, int wn, int lane) {
  const int l16 = lane & 15, quad = lane >> 4;
#pragma unroll
  for (int ks = 0; ks < 2; ++ks) {
    int ko = ks * 32 + quad * 8;
    bf16x8_t ah[4], al[4];
#pragma unroll
    for (int mt = 0; mt < 4; ++mt) {
      ah[mt] = *(const bf16x8_t*)&Ah[wm + mt * 16 + l16][ko];
      al[mt] = *(const bf16x8_t*)&Al[wm + mt * 16 + l16][ko];
    }
#pragma unroll
    for (int nt = 0; nt < 4; ++nt) {
      bf16x8_t bh = *(const bf16x8_t*)&Bh[wn + nt * 16 + l16][ko];
      bf16x8_t bl = *(const bf16x8_t*)&Bl[wn + nt * 16 + l16][ko];
#pragma unroll
      for (int mt = 0; mt < 4; ++mt) {
        acc[mt][nt] = MFMA16(ah[mt], bh, acc[mt][nt]);
        acc[mt][nt] = MFMA16(ah[mt], bl, acc[mt][nt]);
        acc[mt][nt] = MFMA16(al[mt], bh, acc[mt][nt]);
      }
    }
  }
}

// ---------------- conv down k4 s2 p1, 64oc x 64pix, 2x2 waves, K=4096 ------
// Double-buffered LDS, one barrier per chunk.
__global__ __launch_bounds__(256) void k_conv_down_mfma(
    const unsigned* __restrict__ xphl, const unsigned short* __restrict__ wdh,
    const unsigned short* __restrict__ wdl, const float* __restrict__ bias,
    unsigned* __restrict__ xdhl) {
  __shared__ unsigned short Ah[2][64][72], Al[2][64][72];
  __shared__ unsigned short Bh[2][64][72], Bl[2][64][72];
  const int t = threadIdx.x;
  const int pix0 = blockIdx.x * 64, oc0 = blockIdx.y * 64;
  const int bimg = pix0 >> 10, pos = pix0 & 1023;
  const int pl = t & 63, icg = t >> 6;
  const int rem = (pix0 + pl) & 1023;
  const int oy = rem >> 5, ox = rem & 31;
  const unsigned* xb = xphl + ((size_t)bimg * 256 + icg) * 4488 + (oy * 2) * 68 + ox * 2;
  const int wave = t >> 6, lane = t & 63, l16 = lane & 15, quad = lane >> 4;
  const int wm = (wave & 1) * 32, wn = (wave >> 1) * 32;
  const int ar = t >> 2, ac = (t & 3) * 16;
  const unsigned short* wra = wdh + (size_t)(oc0 + ar) * 4096 + ac;
  const unsigned short* wrl = wdl + (size_t)(oc0 + ar) * 4096 + ac;
  f32x4_t acc[2][2] = {};
  bf16x8_t a0, a1, a2, a3;
  uint2 u01[4], u23[4];
  // prologue: chunk kb=0
  a0 = *(const bf16x8_t*)(wra);
  a1 = *(const bf16x8_t*)(wra + 8);
  a2 = *(const bf16x8_t*)(wrl);
  a3 = *(const bf16x8_t*)(wrl + 8);
#pragma unroll
  for (int r = 0; r < 4; ++r) {
    u01[r] = *(const uint2*)(xb + r * 68);
    u23[r] = *(const uint2*)(xb + r * 68 + 2);
  }
  int cur = 0;
  for (int kb = 0; kb < 4096; kb += 64) {
    unsigned hp[8], lp[8];
#pragma unroll
    for (int r = 0; r < 4; ++r) {
      hp[2 * r]     = pk_h(u01[r].x, u01[r].y);
      lp[2 * r]     = pk_l(u01[r].x, u01[r].y);
      hp[2 * r + 1] = pk_h(u23[r].x, u23[r].y);
      lp[2 * r + 1] = pk_l(u23[r].x, u23[r].y);
    }
    *(bf16x8_t*)&Ah[cur][ar][ac] = a0;
    *(bf16x8_t*)&Ah[cur][ar][ac + 8] = a1;
    *(bf16x8_t*)&Al[cur][ar][ac] = a2;
    *(bf16x8_t*)&Al[cur][ar][ac + 8] = a3;
    *(uint4*)&Bh[cur][pl][icg * 16] = make_uint4(hp[0], hp[1], hp[2], hp[3]);
    *(uint4*)&Bh[cur][pl][icg * 16 + 8] = make_uint4(hp[4], hp[5], hp[6], hp[7]);
    *(uint4*)&Bl[cur][pl][icg * 16] = make_uint4(lp[0], lp[1], lp[2], lp[3]);
    *(uint4*)&Bl[cur][pl][icg * 16 + 8] = make_uint4(lp[4], lp[5], lp[6], lp[7]);
    if (kb + 64 < 4096) {  // prefetch next chunk into registers
      xb += 4 * 4488;
      a0 = *(const bf16x8_t*)(wra + kb + 64);
      a1 = *(const bf16x8_t*)(wra + kb + 64 + 8);
      a2 = *(const bf16x8_t*)(wrl + kb + 64);
      a3 = *(const bf16x8_t*)(wrl + kb + 64 + 8);
#pragma unroll
      for (int r = 0; r < 4; ++r) {
        u01[r] = *(const uint2*)(xb + r * 68);
        u23[r] = *(const uint2*)(xb + r * 68 + 2);
      }
    }
    __syncthreads();  // buf[cur] writes visible; prior reads of buf[cur] done
    mfma_tile2x2(Ah[cur], Al[cur], Bh[cur], Bl[cur], acc, wm, wn, lane);
    cur ^= 1;
  }
#pragma unroll
  for (int mt = 0; mt < 2; ++mt)
#pragma unroll
    for (int r = 0; r < 4; ++r) {
      int oc = oc0 + wm + mt * 16 + quad * 4 + r;
      float bv = bias[oc];
#pragma unroll
      for (int nt = 0; nt < 2; ++nt)
        xdhl[((size_t)(bimg * 256 + oc)) * 1024 + pos + wn + nt * 16 + l16] =
            cvtpack(acc[mt][nt][r] + bv);
    }
}

// ---------------- qkv projection -------------------------------------------
template <int MODE>
__global__ __launch_bounds__(256) void k_qkv_mfma(
    const unsigned* __restrict__ srcp, const float* __restrict__ srcf,
    const unsigned short* __restrict__ wh, const unsigned short* __restrict__ wl,
    const float* __restrict__ bq, const int* __restrict__ topk,
    unsigned short* __restrict__ qh, unsigned short* __restrict__ ql,
    unsigned short* __restrict__ kh, unsigned short* __restrict__ kl,
    unsigned short* __restrict__ vth, unsigned short* __restrict__ vtl) {
  __shared__ unsigned short Ah[64][72], Al[64][72];
  const int t = threadIdx.x;
  const int tok0 = blockIdx.x * 64;
  const int pair = blockIdx.y;
  const int b = pair >> 2, h = pair & 3;
  const int tokl = t & 63, dg = t >> 6;
  unsigned hp[8], lp[8];
  if (MODE == 0) {
    const unsigned* base = srcp + ((size_t)(b * 256 + h * 64 + dg * 16)) * 1024 + tok0 + tokl;
    unsigned u[16];
#pragma unroll
    for (int j = 0; j < 16; ++j) u[j] = base[(size_t)j * 1024];
#pragma unroll
    for (int j = 0; j < 8; ++j) {
      hp[j] = pk_h(u[2 * j], u[2 * j + 1]);
      lp[j] = pk_l(u[2 * j], u[2 * j + 1]);
    }
  } else {
    int tok = tok0 + tokl;
    int pp = topk[pair * 256 + (tok >> 2)];
    int py = (tok >> 1) & 1, px = tok & 1;
    int ry = (pp >> 5) * 2 + py, rx = (pp & 31) * 2 + px;
    const float* base = srcf + ((size_t)(b * 256 + h * 64 + dg * 16)) * 4096 + ry * 64 + rx;
    float fv[16];
#pragma unroll
    for (int j = 0; j < 16; ++j) fv[j] = base[(size_t)j * 4096];
#pragma unroll
    for (int j = 0; j < 8; ++j) cvt2(fv[2 * j], fv[2 * j + 1], hp[j], lp[j]);
  }
  *(uint4*)&Ah[tokl][dg * 16] = make_uint4(hp[0], hp[1], hp[2], hp[3]);
  *(uint4*)&Ah[tokl][dg * 16 + 8] = make_uint4(hp[4], hp[5], hp[6], hp[7]);
  *(uint4*)&Al[tokl][dg * 16] = make_uint4(lp[0], lp[1], lp[2], lp[3]);
  *(uint4*)&Al[tokl][dg * 16 + 8] = make_uint4(lp[4], lp[5], lp[6], lp[7]);
  __syncthreads();
  const int wave = t >> 6, lane = t & 63, l16 = lane & 15, quad = lane >> 4;
  f32x4_t acc[4][3] = {};
#pragma unroll
  for (int ks = 0; ks < 2; ++ks) {
    int ko = ks * 32 + quad * 8;
    bf16x8_t bh0[3], bl0[3];
#pragma unroll
    for (int nt = 0; nt < 3; ++nt) {
      int col = wave * 48 + nt * 16 + l16;
      bh0[nt] = *(const bf16x8_t*)(wh + col * 64 + ko);
      bl0[nt] = *(const bf16x8_t*)(wl + col * 64 + ko);
    }
#pragma unroll
    for (int mt = 0; mt < 4; ++mt) {
      bf16x8_t ah = *(const bf16x8_t*)&Ah[mt * 16 + l16][ko];
      bf16x8_t al = *(const bf16x8_t*)&Al[mt * 16 + l16][ko];
#pragma unroll
      for (int nt = 0; nt < 3; ++nt) {
        acc[mt][nt] = MFMA16(ah, bh0[nt], acc[mt][nt]);
        acc[mt][nt] = MFMA16(ah, bl0[nt], acc[mt][nt]);
        acc[mt][nt] = MFMA16(al, bh0[nt], acc[mt][nt]);
      }
    }
  }
#pragma unroll
  for (int nt = 0; nt < 3; ++nt) {
    int col = wave * 48 + nt * 16 + l16;
    float bqv = bq[col];
    if (col < 64) bqv *= 0.125f;
#pragma unroll
    for (int mt = 0; mt < 4; ++mt) {
#pragma unroll
      for (int r = 0; r < 4; ++r) {
        int tok = tok0 + mt * 16 + quad * 4 + r;
        float val = acc[mt][nt][r] + bqv;
        unsigned short hh, ll;
        cvt1(val, hh, ll);
        if (col < 64) {
          size_t o = ((size_t)pair * 1024 + tok) * 64 + col;
          qh[o] = hh; ql[o] = ll;
        } else if (col < 128) {
          size_t o = ((size_t)pair * 1024 + tok) * 64 + (col - 64);
          kh[o] = hh; kl[o] = ll;
        } else {
          size_t o = ((size_t)pair * 64 + (col - 128)) * 1024 + tok;
          vth[o] = hh; vtl[o] = ll;
        }
      }
    }
  }
}

// ---------------- coarse fused attention (score path, bit-identical) -------
// Q panel in registers; K (pass1) / K+V (pass2) register-prefetched.
__global__ __launch_bounds__(256, 2) void k_attn_coarse(
    const unsigned short* __restrict__ qh, const unsigned short* __restrict__ ql,
    const unsigned short* __restrict__ kh, const unsigned short* __restrict__ kl,
    const unsigned short* __restrict__ vth, const unsigned short* __restrict__ vtl,
    float* __restrict__ score, unsigned* __restrict__ outc) {
  __shared__ __align__(16) unsigned short Kb[2][64][72];
  __shared__ __align__(16) unsigned short Vb[2][64][72];
  __shared__ __align__(16) unsigned short Pb[2][64][72];
  __shared__ float mlW[4][2][64];
  __shared__ float mC[64], lC[64];
  __shared__ float colsum[1024];
  const int t = threadIdx.x;
  const int q0 = blockIdx.x * 64;
  const int pair = blockIdx.y;
  const int wave = t >> 6, lane = t & 63;
  const int l16 = lane & 15, quad = lane >> 4;
  const int wm = wave * 16;
  const int sr = t >> 3, skc = (t & 7) * 8;

  const size_t qbase = ((size_t)pair * 1024 + q0) * 64;
  // Q fragments in registers: B-operand rows nt*16+l16, k-slice ks*32+quad*8
  bf16x8_t qh_r[2][4], ql_r[2][4];
#pragma unroll
  for (int ks = 0; ks < 2; ++ks)
#pragma unroll
    for (int nt = 0; nt < 4; ++nt) {
      int row = nt * 16 + l16, col = ks * 32 + quad * 8;
      qh_r[ks][nt] = *(const bf16x8_t*)(qh + qbase + (size_t)row * 64 + col);
      ql_r[ks][nt] = *(const bf16x8_t*)(ql + qbase + (size_t)row * 64 + col);
    }
#pragma unroll
  for (int i = 0; i < 4; ++i) colsum[t + i * 256] = 0.f;

  const size_t kmbase = (size_t)pair * 1024 * 64;
  const size_t vbase = (size_t)pair * 64 * 1024;

  // prologue prefetch: pass-1 chunk 0
  bf16x8_t pk0[2], pk1[2];
#pragma unroll
  for (int i = 0; i < 2; ++i) {
    int r = sr + i * 32;
    pk0[i] = *(const bf16x8_t*)(kh + kmbase + (size_t)r * 64 + skc);
    pk1[i] = *(const bf16x8_t*)(kl + kmbase + (size_t)r * 64 + skc);
  }

  // ---- pass 1: online (m,l), numerics identical ----
  float mrun[4] = {-1e30f, -1e30f, -1e30f, -1e30f};
  float lrun[4] = {0.f, 0.f, 0.f, 0.f};
  for (int kb = 0; kb < 1024; kb += 64) {
    __syncthreads();
#pragma unroll
    for (int i = 0; i < 2; ++i) {
      int r = sr + i * 32;
      *(bf16x8_t*)&Kb[0][r][skc] = pk0[i];
      *(bf16x8_t*)&Kb[1][r][skc] = pk1[i];
    }
    if (kb + 64 < 1024) {  // prefetch next chunk
#pragma unroll
      for (int i = 0; i < 2; ++i) {
        int r = sr + i * 32;
        pk0[i] = *(const bf16x8_t*)(kh + kmbase + (size_t)(kb + 64 + r) * 64 + skc);
        pk1[i] = *(const bf16x8_t*)(kl + kmbase + (size_t)(kb + 64 + r) * 64 + skc);
      }
    }
    __syncthreads();
    f32x4_t acc[4] = {};
    mfma_chunk_regB(Kb[0], Kb[1], qh_r, ql_r, acc, wm, lane);
#pragma unroll
    for (int nt = 0; nt < 4; ++nt) {
      float m0 = fmaxf(fmaxf(acc[nt][0], acc[nt][1]), fmaxf(acc[nt][2], acc[nt][3]));
      m0 = fmaxf(m0, __shfl_xor(m0, 16));
      m0 = fmaxf(m0, __shfl_xor(m0, 32));
      float mn = fmaxf(mrun[nt], m0);
      float s0 = __expf(acc[nt][0] - mn) + __expf(acc[nt][1] - mn) +
                 __expf(acc[nt][2] - mn) + __expf(acc[nt][3] - mn);
      s0 += __shfl_xor(s0, 16);
      s0 += __shfl_xor(s0, 32);
      lrun[nt] = lrun[nt] * __expf(mrun[nt] - mn) + s0;
      mrun[nt] = mn;
    }
  }
  // issue pass-2 chunk-0 prefetch (K and V) before the m/l merge section
  bf16x8_t pv0[2], pv1[2];
#pragma unroll
  for (int i = 0; i < 2; ++i) {
    int r = sr + i * 32;
    pk0[i] = *(const bf16x8_t*)(kh + kmbase + (size_t)r * 64 + skc);
    pk1[i] = *(const bf16x8_t*)(kl + kmbase + (size_t)r * 64 + skc);
    pv0[i] = *(const bf16x8_t*)(vth + vbase + (size_t)r * 1024 + skc);
    pv1[i] = *(const bf16x8_t*)(vtl + vbase + (size_t)r * 1024 + skc);
  }
  __syncthreads();
  if (quad == 0) {
#pragma unroll
    for (int nt = 0; nt < 4; ++nt) {
      mlW[wave][0][nt * 16 + l16] = mrun[nt];
      mlW[wave][1][nt * 16 + l16] = lrun[nt];
    }
  }
  __syncthreads();
  if (t < 64) {
    float m0 = mlW[0][0][t], m1 = mlW[1][0][t], m2 = mlW[2][0][t], m3 = mlW[3][0][t];
    float mm = fmaxf(fmaxf(m0, m1), fmaxf(m2, m3));
    float ll = mlW[0][1][t] * __expf(m0 - mm) + mlW[1][1][t] * __expf(m1 - mm) +
               mlW[2][1][t] * __expf(m2 - mm) + mlW[3][1][t] * __expf(m3 - mm);
    mC[t] = mm;
    lC[t] = 1.0f / ll;
  }
  __syncthreads();
  float mq[4], il[4];
#pragma unroll
  for (int nt = 0; nt < 4; ++nt) {
    mq[nt] = mC[nt * 16 + l16];
    il[nt] = lC[nt * 16 + l16];
  }

  // ---- pass 2: recompute, final P, colsum, PV. 3 barriers/chunk ----
  f32x4_t accO[4] = {};
  for (int kb = 0; kb < 1024; kb += 64) {
    __syncthreads();  // prev PV done reading Pb/Vb
#pragma unroll
    for (int i = 0; i < 2; ++i) {
      int r = sr + i * 32;
      *(bf16x8_t*)&Kb[0][r][skc] = pk0[i];
      *(bf16x8_t*)&Kb[1][r][skc] = pk1[i];
      *(bf16x8_t*)&Vb[0][r][skc] = pv0[i];
      *(bf16x8_t*)&Vb[1][r][skc] = pv1[i];
    }
    if (kb + 64 < 1024) {  // prefetch next chunk
#pragma unroll
      for (int i = 0; i < 2; ++i) {
        int r = sr + i * 32;
        pk0[i] = *(const bf16x8_t*)(kh + kmbase + (size_t)(kb + 64 + r) * 64 + skc);
        pk1[i] = *(const bf16x8_t*)(kl + kmbase + (size_t)(kb + 64 + r) * 64 + skc);
        pv0[i] = *(const bf16x8_t*)(vth + vbase + (size_t)r * 1024 + kb + 64 + skc);
        pv1[i] = *(const bf16x8_t*)(vtl + vbase + (size_t)r * 1024 + kb + 64 + skc);
      }
    }
    __syncthreads();
    f32x4_t acc[4] = {};
    mfma_chunk_regB(Kb[0], Kb[1], qh_r, ql_r, acc, wm, lane);
    float P[4][4];
#pragma unroll
    for (int nt = 0; nt < 4; ++nt)
#pragma unroll
      for (int r = 0; r < 4; ++r) P[nt][r] = __expf(acc[nt][r] - mq[nt]) * il[nt];
#pragma unroll
    for (int r = 0; r < 4; ++r) {
      float cs = P[0][r] + P[1][r] + P[2][r] + P[3][r];
      cs += __shfl_xor(cs, 1);
      cs += __shfl_xor(cs, 2);
      cs += __shfl_xor(cs, 4);
      cs += __shfl_xor(cs, 8);
      if (l16 == 0) colsum[kb + wm + quad * 4 + r] += cs;
    }
#pragma unroll
    for (int nt = 0; nt < 4; ++nt) {
      unsigned h01, l01, h23, l23;
      cvt2(P[nt][0], P[nt][1], h01, l01);
      cvt2(P[nt][2], P[nt][3], h23, l23);
      *(uint2*)&Pb[0][nt * 16 + l16][wm + quad * 4] = make_uint2(h01, h23);
      *(uint2*)&Pb[1][nt * 16 + l16][wm + quad * 4] = make_uint2(l01, l23);
    }
    __syncthreads();  // Pb visible
    mfma_chunk(Pb[0], Pb[1], Vb[0], Vb[1], accO, wm, lane);
  }
  __syncthreads();

#pragma unroll
  for (int i = 0; i < 4; ++i)
    atomicAdd(&score[pair * 1024 + t + i * 256], colsum[t + i * 256]);
  float (*Tr)[68] = reinterpret_cast<float(*)[68]>(&Pb[0][0][0]);
#pragma unroll
  for (int nt = 0; nt < 4; ++nt)
#pragma unroll
    for (int r = 0; r < 4; ++r)
      Tr[nt * 16 + l16][wm + quad * 4 + r] = accO[nt][r];
  __syncthreads();
  const int b = pair >> 2, h = pair & 3;
#pragma unroll
  for (int i = 0; i < 16; ++i) {
    int e = t + i * 256;
    int d = e >> 6, ql_ = e & 63;
    int pix = q0 + ql_;
    int iy = (pix >> 5) + 1, ix = (pix & 31) + 1;
    outc[((size_t)(b * 256 + h * 64 + d)) * 1156 + iy * 34 + ix] = cvtpack(Tr[d][ql_]);
  }
}

// ---------------- fine fused attention: single-pass online flash -----------
// Q panel in registers; K+V register-prefetched.
__global__ __launch_bounds__(256, 2) void k_attn_fine(
    const unsigned short* __restrict__ qh, const unsigned short* __restrict__ ql,
    const unsigned short* __restrict__ kh, const unsigned short* __restrict__ kl,
    const unsigned short* __restrict__ vth, const unsigned short* __restrict__ vtl,
    float* __restrict__ outf) {
  __shared__ __align__(16) unsigned short Kb[2][64][72];
  __shared__ __align__(16) unsigned short Vb[2][64][72];
  __shared__ __align__(16) unsigned short Pb[2][64][72];
  __shared__ float m_run[64], l_run[64], alphaS[64];
  __shared__ float mWc[4][64], sWc[4][64];
  const int t = threadIdx.x;
  const int q0 = blockIdx.x * 64;
  const int pair = blockIdx.y;
  const int wave = t >> 6, lane = t & 63;
  const int l16 = lane & 15, quad = lane >> 4;
  const int wm = wave * 16;
  const int sr = t >> 3, skc = (t & 7) * 8;

  const size_t qbase = ((size_t)pair * 1024 + q0) * 64;
  bf16x8_t qh_r[2][4], ql_r[2][4];
#pragma unroll
  for (int ks = 0; ks < 2; ++ks)
#pragma unroll
    for (int nt = 0; nt < 4; ++nt) {
      int row = nt * 16 + l16, col = ks * 32 + quad * 8;
      qh_r[ks][nt] = *(const bf16x8_t*)(qh + qbase + (size_t)row * 64 + col);
      ql_r[ks][nt] = *(const bf16x8_t*)(ql + qbase + (size_t)row * 64 + col);
    }
  if (t < 64) { m_run[t] = -1e30f; l_run[t] = 0.f; }

  const size_t kmbase = (size_t)pair * 1024 * 64;
  const size_t vbase = (size_t)pair * 64 * 1024;

  // prologue prefetch: chunk 0
  bf16x8_t pk0[2], pk1[2], pv0[2], pv1[2];
#pragma unroll
  for (int i = 0; i < 2; ++i) {
    int r = sr + i * 32;
    pk0[i] = *(const bf16x8_t*)(kh + kmbase + (size_t)r * 64 + skc);
    pk1[i] = *(const bf16x8_t*)(kl + kmbase + (size_t)r * 64 + skc);
    pv0[i] = *(const bf16x8_t*)(vth + vbase + (size_t)r * 1024 + skc);
    pv1[i] = *(const bf16x8_t*)(vtl + vbase + (size_t)r * 1024 + skc);
  }

  f32x4_t accO[4] = {};
  for (int kb = 0; kb < 1024; kb += 64) {
    __syncthreads();  // prev PV done reading Pb/Vb; m/l arrays consumed
#pragma unroll
    for (int i = 0; i < 2; ++i) {
      int r = sr + i * 32;
      *(bf16x8_t*)&Kb[0][r][skc] = pk0[i];
      *(bf16x8_t*)&Kb[1][r][skc] = pk1[i];
      *(bf16x8_t*)&Vb[0][r][skc] = pv0[i];
      *(bf16x8_t*)&Vb[1][r][skc] = pv1[i];
    }
    if (kb + 64 < 1024) {  // prefetch next chunk
#pragma unroll
      for (int i = 0; i < 2; ++i) {
        int r = sr + i * 32;
        pk0[i] = *(const bf16x8_t*)(kh + kmbase + (size_t)(kb + 64 + r) * 64 + skc);
        pk1[i] = *(const bf16x8_t*)(kl + kmbase + (size_t)(kb + 64 + r) * 64 + skc);
        pv0[i] = *(const bf16x8_t*)(vth + vbase + (size_t)r * 1024 + kb + 64 + skc);
        pv1[i] = *(const bf16x8_t*)(vtl + vbase + (size_t)r * 1024 + kb + 64 + skc);
      }
    }
    __syncthreads();
    f32x4_t acc[4] = {};
    mfma_chunk_regB(Kb[0], Kb[1], qh_r, ql_r, acc, wm, lane);  // S^T tile
    // per-wave k-max per q
#pragma unroll
    for (int nt = 0; nt < 4; ++nt) {
      float m0 = fmaxf(fmaxf(acc[nt][0], acc[nt][1]), fmaxf(acc[nt][2], acc[nt][3]));
      m0 = fmaxf(m0, __shfl_xor(m0, 16));
      m0 = fmaxf(m0, __shfl_xor(m0, 32));
      if (quad == 0) mWc[wave][nt * 16 + l16] = m0;
    }
    __syncthreads();
    if (t < 64) {
      float mn = fmaxf(fmaxf(fmaxf(mWc[0][t], mWc[1][t]), fmaxf(mWc[2][t], mWc[3][t])),
                       m_run[t]);
      alphaS[t] = __expf(m_run[t] - mn);
      m_run[t] = mn;
    }
    __syncthreads();
    // P = exp(s - m_new); write Pb; per-wave partial l sums; rescale accO
    float P[4][4];
#pragma unroll
    for (int nt = 0; nt < 4; ++nt) {
      float mn = m_run[nt * 16 + l16];
#pragma unroll
      for (int r = 0; r < 4; ++r) P[nt][r] = __expf(acc[nt][r] - mn);
      float s0 = P[nt][0] + P[nt][1] + P[nt][2] + P[nt][3];
      s0 += __shfl_xor(s0, 16);
      s0 += __shfl_xor(s0, 32);
      if (quad == 0) sWc[wave][nt * 16 + l16] = s0;
      unsigned h01, l01, h23, l23;
      cvt2(P[nt][0], P[nt][1], h01, l01);
      cvt2(P[nt][2], P[nt][3], h23, l23);
      *(uint2*)&Pb[0][nt * 16 + l16][wm + quad * 4] = make_uint2(h01, h23);
      *(uint2*)&Pb[1][nt * 16 + l16][wm + quad * 4] = make_uint2(l01, l23);
    }
#pragma unroll
    for (int r = 0; r < 4; ++r) {
      float a = alphaS[wm + quad * 4 + r];
#pragma unroll
      for (int nt = 0; nt < 4; ++nt) accO[nt][r] *= a;
    }
    __syncthreads();  // Pb + sWc visible
    if (t < 64)
      l_run[t] = l_run[t] * alphaS[t] + (sWc[0][t] + sWc[1][t] + sWc[2][t] + sWc[3][t]);
    mfma_chunk(Pb[0], Pb[1], Vb[0], Vb[1], accO, wm, lane);  // O += P~ @ V
  }
  __syncthreads();
#pragma unroll
  for (int r = 0; r < 4; ++r) {
    float invl = 1.0f / l_run[wm + quad * 4 + r];
    int qm = q0 + wm + quad * 4 + r;
#pragma unroll
    for (int nt = 0; nt < 4; ++nt)
      outf[((size_t)pair * 1024 + qm) * 64 + nt * 16 + l16] = accO[nt][r] * invl;
  }
}

// ---------------- per-pair top-256 via bitonic sort ------------------------
__global__ __launch_bounds__(256) void k_topk(
    const float* __restrict__ score, int* __restrict__ idx) {
  __shared__ unsigned long long key[1024];
  const int pair = blockIdx.x;
  const int t = threadIdx.x;
#pragma unroll
  for (int j = 0; j < 4; ++j) {
    int i = t + j * 256;
    unsigned u = __float_as_uint(score[pair * 1024 + i]);
    u = u ^ ((u & 0x80000000u) ? 0xFFFFFFFFu : 0x80000000u);
    u = ~u;
    key[i] = ((unsigned long long)u << 32) | (unsigned)i;
  }
  __syncthreads();
  for (int k = 2; k <= 1024; k <<= 1) {
    for (int j = k >> 1; j > 0; j >>= 1) {
      for (int w = 0; w < 4; ++w) {
        int i = t + w * 256;
        int l = i ^ j;
        if (l > i) {
          bool up = ((i & k) == 0);
          unsigned long long a = key[i], b = key[l];
          if ((a > b) == up) { key[i] = b; key[l] = a; }
        }
      }
      __syncthreads();
    }
  }
  idx[pair * 256 + t] = (int)(key[t] & 0xFFFFFFFFu);
}

// ---------------- convT: 128oc x 128pix tile, 4 classes, 4x4 blocking ------
__global__ __launch_bounds__(256) void k_convT_mfma(
    const unsigned* __restrict__ inp, const unsigned short* __restrict__ wth,
    const unsigned short* __restrict__ wtl, const float* __restrict__ bias,
    float* __restrict__ out) {
  __shared__ unsigned short Ah[128][72], Al[128][72];
  __shared__ unsigned short Bh[128][72], Bl[128][72];
  const int t = threadIdx.x;
  const int pix0 = blockIdx.x * 128;
  const int oc0 = blockIdx.y * 128;
  const int cls = blockIdx.z;
  const int ry = cls >> 1, rx = cls & 1;
  const int b = pix0 >> 10;
  const int wave = t >> 6, lane = t & 63;
  const int l16 = lane & 15, quad = lane >> 4;
  const int wm = (wave & 1) * 64, wn = (wave >> 1) * 64;
  const int pl = t & 127, icg = t >> 7;
  const int remg = (pix0 + pl) & 1023;
  const int tyy = remg >> 5, txx = remg & 31;
  const int ar = t >> 1, ac = (t & 1) * 32;
  const size_t wbase = ((size_t)cls * 256 + oc0 + ar) * 1024 + ac;
  f32x4_t acc[4][4] = {};
  bf16x8_t awh[4], awl[4];
  unsigned u[32];
  // prologue: chunk kb=0 (tap 0 -> tk=0, txi=0; ic0=0)
  {
    const int iy = tyy + ry + 1, ix = txx + rx + 1;
    const unsigned* p = inp + (size_t)(b * 256 + icg * 32) * 1156 + iy * 34 + ix;
#pragma unroll
    for (int j = 0; j < 32; ++j) u[j] = p[(size_t)j * 1156];
#pragma unroll
    for (int j = 0; j < 4; ++j) {
      awh[j] = *(const bf16x8_t*)(wth + wbase + j * 8);
      awl[j] = *(const bf16x8_t*)(wtl + wbase + j * 8);
    }
  }
  for (int kb = 0; kb < 1024; kb += 64) {
    unsigned hp[16], lpk[16];
#pragma unroll
    for (int j = 0; j < 16; ++j) {
      hp[j] = pk_h(u[2 * j], u[2 * j + 1]);
      lpk[j] = pk_l(u[2 * j], u[2 * j + 1]);
    }
    __syncthreads();
#pragma unroll
    for (int j = 0; j < 4; ++j) {
      *(bf16x8_t*)&Ah[ar][ac + j * 8] = awh[j];
      *(bf16x8_t*)&Al[ar][ac + j * 8] = awl[j];
    }
    {
      int kc = icg * 32;
      *(uint4*)&Bh[pl][kc] = make_uint4(hp[0], hp[1], hp[2], hp[3]);
      *(uint4*)&Bh[pl][kc + 8] = make_uint4(hp[4], hp[5], hp[6], hp[7]);
      *(uint4*)&Bh[pl][kc + 16] = make_uint4(hp[8], hp[9], hp[10], hp[11]);
      *(uint4*)&Bh[pl][kc + 24] = make_uint4(hp[12], hp[13], hp[14], hp[15]);
      *(uint4*)&Bl[pl][kc] = make_uint4(lpk[0], lpk[1], lpk[2], lpk[3]);
      *(uint4*)&Bl[pl][kc + 8] = make_uint4(lpk[4], lpk[5], lpk[6], lpk[7]);
      *(uint4*)&Bl[pl][kc + 16] = make_uint4(lpk[8], lpk[9], lpk[10], lpk[11]);
      *(uint4*)&Bl[pl][kc + 24] = make_uint4(lpk[12], lpk[13], lpk[14], lpk[15]);
    }
    if (kb + 64 < 1024) {  // prefetch next chunk into registers
      const int kn = kb + 64;
      const int tap = kn >> 8, ic0 = kn & 255;
      const int tk = tap >> 1, txi = tap & 1;
      const int iy = tyy + ry + 1 - tk, ix = txx + rx + 1 - txi;
      const unsigned* p = inp + (size_t)(b * 256 + ic0 + icg * 32) * 1156 + iy * 34 + ix;
#pragma unroll
      for (int j = 0; j < 32; ++j) u[j] = p[(size_t)j * 1156];
#pragma unroll
      for (int j = 0; j < 4; ++j) {
        awh[j] = *(const bf16x8_t*)(wth + wbase + kn + j * 8);
        awl[j] = *(const bf16x8_t*)(wtl + wbase + kn + j * 8);
      }
    }
    __syncthreads();
    mfma_tile4x4(Ah, Al, Bh, Bl, acc, wm, wn, lane);
  }
#pragma unroll
  for (int mt = 0; mt < 4; ++mt)
#pragma unroll
    for (int r = 0; r < 4; ++r) {
      int oc = oc0 + wm + mt * 16 + quad * 4 + r;
      float bvs = bias[oc];
#pragma unroll
      for (int nt = 0; nt < 4; ++nt) {
        int pix = pix0 + wn + nt * 16 + l16;
        int rem2 = pix & 1023;
        int y = (rem2 >> 5) * 2 + ry, xx = (rem2 & 31) * 2 + rx;
        out[((size_t)(b * 256 + oc) * 64 + y) * 64 + xx] = acc[mt][nt][r] + bvs;
      }
    }
}

// ---------------- scatter fine outputs into y ------------------------------
__global__ __launch_bounds__(256) void k_scatter(
    const float* __restrict__ outf, const int* __restrict__ idx,
    float* __restrict__ y) {
  int g = blockIdx.x * 256 + threadIdx.x;
  int pair = g >> 16;
  int rem = g & 65535;
  int tok = rem >> 6, d = rem & 63;
  int b = pair >> 2, h = pair & 3;
  int pp = idx[pair * 256 + (tok >> 2)];
  int py = (tok >> 1) & 1, px = tok & 1;
  int ry = (pp >> 5) * 2 + py, rx = (pp & 31) * 2 + px;
  y[((size_t)(b * 256 + h * 64 + d) * 64 + ry) * 64 + rx] += outf[g];
}

// ---------------- depthwise 3x3 + BN + relu6 -> packed yd ------------------
__global__ __launch_bounds__(256) void k_dwconv(
    const float* __restrict__ y, const float* __restrict__ wdw,
    const float* __restrict__ g, const float* __restrict__ bb,
    const float* __restrict__ m, const float* __restrict__ vv,
    unsigned* __restrict__ ydhl) {
  int gi = blockIdx.x * 256 + threadIdx.x;
  int x = gi & 63, yy = (gi >> 6) & 63, ch = (gi >> 12) & 255, b = gi >> 20;
  const float* plane = y + (size_t)(b * 256 + ch) * 4096;
  const float* wc = wdw + ch * 9;
  float s = 0.f;
#pragma unroll
  for (int ky = 0; ky < 3; ++ky) {
    int iy = yy + ky - 1;
    if (iy < 0 || iy >= 64) continue;
#pragma unroll
    for (int kx = 0; kx < 3; ++kx) {
      int ix = x + kx - 1;
      if (ix < 0 || ix >= 64) continue;
      s = fmaf(plane[iy * 64 + ix], wc[ky * 3 + kx], s);
    }
  }
  float sc = g[ch] * rsqrtf(vv[ch] + EPS_);
  float val = s * sc + (bb[ch] - m[ch] * sc);
  ydhl[gi] = cvtpack(fminf(fmaxf(val, 0.f), 6.f));
}

// ---------------- pointwise 1x1 + BN + relu6, 128oc x 128pix, 4x4 ----------
__global__ __launch_bounds__(256) void k_pw_mfma(
    const unsigned* __restrict__ ydhl, const unsigned short* __restrict__ wh,
    const unsigned short* __restrict__ wl, const float* __restrict__ g,
    const float* __restrict__ bb, const float* __restrict__ m,
    const float* __restrict__ vv, float* __restrict__ out) {
  __shared__ unsigned short Ah[128][72], Al[128][72];
  __shared__ unsigned short Bh[128][72], Bl[128][72];
  const int t = threadIdx.x;
  const int pix0 = blockIdx.x * 128;
  const int oc0 = blockIdx.y * 128;
  const int b = pix0 >> 12, pos0 = pix0 & 4095;
  const int wave = t >> 6, lane = t & 63;
  const int l16 = lane & 15, quad = lane >> 4;
  const int wm = (wave & 1) * 64, wn = (wave >> 1) * 64;
  const int pl = t & 127, icg = t >> 7;
  const int ar = t >> 1, ac = (t & 1) * 32;
  f32x4_t acc[4][4] = {};
  bf16x8_t awh[4], awl[4];
  unsigned u[32];
  // prologue: chunk kb=0
  {
    const unsigned* p = ydhl + (size_t)(b * 256 + icg * 32) * 4096 + pos0 + pl;
#pragma unroll
    for (int j = 0; j < 32; ++j) u[j] = p[(size_t)j * 4096];
#pragma unroll
    for (int j = 0; j < 4; ++j) {
      awh[j] = *(const bf16x8_t*)(wh + (size_t)(oc0 + ar) * 256 + ac + j * 8);
      awl[j] = *(const bf16x8_t*)(wl + (size_t)(oc0 + ar) * 256 + ac + j * 8);
    }
  }
  for (int kb = 0; kb < 256; kb += 64) {
    unsigned hp[16], lpk[16];
#pragma unroll
    for (int j = 0; j < 16; ++j) {
      hp[j] = pk_h(u[2 * j], u[2 * j + 1]);
      lpk[j] = pk_l(u[2 * j], u[2 * j + 1]);
    }
    __syncthreads();
#pragma unroll
    for (int j = 0; j < 4; ++j) {
      *(bf16x8_t*)&Ah[ar][ac + j * 8] = awh[j];
      *(bf16x8_t*)&Al[ar][ac + j * 8] = awl[j];
    }
    {
      int kc = icg * 32;
      *(uint4*)&Bh[pl][kc] = make_uint4(hp[0], hp[1], hp[2], hp[3]);
      *(uint4*)&Bh[pl][kc + 8] = make_uint4(hp[4], hp[5], hp[6], hp[7]);
      *(uint4*)&Bh[pl][kc + 16] = make_uint4(hp[8], hp[9], hp[10], hp[11]);
      *(uint4*)&Bh[pl][kc + 24] = make_uint4(hp[12], hp[13], hp[14], hp[15]);
      *(uint4*)&Bl[pl][kc] = make_uint4(lpk[0], lpk[1], lpk[2], lpk[3]);
      *(uint4*)&Bl[pl][kc + 8] = make_uint4(lpk[4], lpk[5], lpk[6], lpk[7]);
      *(uint4*)&Bl[pl][kc + 16] = make_uint4(lpk[8], lpk[9], lpk[10], lpk[11]);
      *(uint4*)&Bl[pl][kc + 24] = make_uint4(lpk[12], lpk[13], lpk[14], lpk[15]);
    }
    if (kb + 64 < 256) {  // prefetch next chunk into registers
      const int kn = kb + 64;
      const unsigned* p = ydhl + (size_t)(b * 256 + kn + icg * 32) * 4096 + pos0 + pl;
#pragma unroll
      for (int j = 0; j < 32; ++j) u[j] = p[(size_t)j * 4096];
#pragma unroll
      for (int j = 0; j < 4; ++j) {
        awh[j] = *(const bf16x8_t*)(wh + (size_t)(oc0 + ar) * 256 + kn + ac + j * 8);
        awl[j] = *(const bf16x8_t*)(wl + (size_t)(oc0 + ar) * 256 + kn + ac + j * 8);
      }
    }
    __syncthreads();
    mfma_tile4x4(Ah, Al, Bh, Bl, acc, wm, wn, lane);
  }
#pragma unroll
  for (int mt = 0; mt < 4; ++mt)
#pragma unroll
    for (int r = 0; r < 4; ++r) {
      int oc = oc0 + wm + mt * 16 + quad * 4 + r;
      float sc = g[oc] * rsqrtf(vv[oc] + EPS_);
      float off = bb[oc] - m[oc] * sc;
#pragma unroll
      for (int nt = 0; nt < 4; ++nt) {
        int pix = pos0 + wn + nt * 16 + l16;
        float val = fminf(fmaxf(acc[mt][nt][r] * sc + off, 0.f), 6.f);
        out[(size_t)(b * 256 + oc) * 4096 + pix] = val;
      }
    }
}

// ---------------------------------------------------------------------------
extern "C" void kernel_launch(void* const* d_in, const int* in_sizes, int n_in,
                              void* d_out, int out_size, void* d_ws, size_t ws_size,
                              hipStream_t stream) {
  (void)in_sizes; (void)n_in; (void)out_size; (void)ws_size;
  const float* x       = (const float*)d_in[0];
  const float* w_down  = (const float*)d_in[1];
  const float* b_down  = (const float*)d_in[2];
  const float* w_qkv_c = (const float*)d_in[3];
  const float* b_qkv_c = (const float*)d_in[4];
  const float* w_up    = (const float*)d_in[5];
  const float* b_up    = (const float*)d_in[6];
  const float* w_qkv_f = (const float*)d_in[7];
  const float* b_qkv_f = (const float*)d_in[8];
  const float* w_dw    = (const float*)d_in[9];
  const float* bn_dw_g = (const float*)d_in[10];
  const float* bn_dw_b = (const float*)d_in[11];
  const float* bn_dw_m = (const float*)d_in[12];
  const float* bn_dw_v = (const float*)d_in[13];
  const float* w_pw    = (const float*)d_in[14];
  const float* bn_pw_g = (const float*)d_in[15];
  const float* bn_pw_b = (const float*)d_in[16];
  const float* bn_pw_m = (const float*)d_in[17];
  const float* bn_pw_v = (const float*)d_in[18];

  float* ws = (float*)d_ws;  // offsets in 4-byte units (round 6/8 layout)
  unsigned*       xphl   = (unsigned*)ws;                   // 9,191,424 u
  unsigned*       ydhl   = (unsigned*)ws;                   // alias (xphl dead by then)
  unsigned short* qh     = (unsigned short*)(ws + 33554432);
  unsigned short* ql     = (unsigned short*)(ws + 34603008);
  unsigned short* kh     = (unsigned short*)(ws + 35651584);
  unsigned short* kl     = (unsigned short*)(ws + 36700160);
  unsigned short* vth    = (unsigned short*)(ws + 37748736);
  unsigned short* vtl    = (unsigned short*)(ws + 38797312);
  unsigned*       xdhl   = (unsigned*)(ws + 39845888);      // 2,097,152 u
  unsigned*       outcphl= (unsigned*)(ws + 41943040);      // 2,367,488 u
  float*          coarse = ws + 44310528;                   // 8,388,608 f
  float*          outf   = ws + 52699136;                   // 2,097,152 f
  float*          score  = ws + 54796288;                   // 32,768 f
  unsigned short* wdh    = (unsigned short*)(ws + 54829056);
  unsigned short* wdl    = (unsigned short*)(ws + 55353344);
  unsigned short* wt_hi  = (unsigned short*)(ws + 55877632);
  unsigned short* wt_lo  = (unsigned short*)(ws + 56401920);
  unsigned short* wpw_hi = (unsigned short*)(ws + 56926208);
  unsigned short* wpw_lo = (unsigned short*)(ws + 56958976);
  unsigned short* wqh_c  = (unsigned short*)(ws + 56991744);
  unsigned short* wql_c  = (unsigned short*)(ws + 56997888);
  unsigned short* wqh_f  = (unsigned short*)(ws + 57004032);
  unsigned short* wql_f  = (unsigned short*)(ws + 57010176);
  int*            idx    = (int*)(ws + 57016320);           // 8,192 int

  hipMemsetAsync(score, 0, 32768 * sizeof(float), stream);
  hipMemsetAsync(outcphl, 0, (size_t)2367488 * sizeof(unsigned), stream);
  k_pad_x<<<2048, 256, 0, stream>>>(x, xphl);
  k_cvt_wdown<<<4096, 256, 0, stream>>>(w_down, wdh, wdl);
  k_cvt_wqkv<<<48, 256, 0, stream>>>(w_qkv_c, wqh_c, wql_c);
  k_cvt_wqkv<<<48, 256, 0, stream>>>(w_qkv_f, wqh_f, wql_f);
  k_cvt_wup<<<4096, 256, 0, stream>>>(w_up, wt_hi, wt_lo);
  k_cvt_wpw<<<256, 256, 0, stream>>>(w_pw, wpw_hi, wpw_lo);

  k_conv_down_mfma<<<dim3(128, 4), 256, 0, stream>>>(xphl, wdh, wdl, b_down, xdhl);
  k_qkv_mfma<0><<<dim3(16, 32), 256, 0, stream>>>(xdhl, nullptr, wqh_c, wql_c, b_qkv_c,
                                                  nullptr, qh, ql, kh, kl, vth, vtl);
  k_attn_coarse<<<dim3(16, 32), 256, 0, stream>>>(qh, ql, kh, kl, vth, vtl, score, outcphl);
  k_topk<<<32, 256, 0, stream>>>(score, idx);
  k_convT_mfma<<<dim3(64, 2, 4), 256, 0, stream>>>(outcphl, wt_hi, wt_lo, b_up, coarse);

  k_qkv_mfma<1><<<dim3(16, 32), 256, 0, stream>>>(nullptr, coarse, wqh_f, wql_f, b_qkv_f,
                                                  idx, qh, ql, kh, kl, vth, vtl);
  k_attn_fine<<<dim3(16, 32), 256, 0, stream>>>(qh, ql, kh, kl, vth, vtl, outf);
  k_scatter<<<8192, 256, 0, stream>>>(outf, idx, coarse);
  k_dwconv<<<32768, 256, 0, stream>>>(coarse, w_dw, bn_dw_g, bn_dw_b, bn_dw_m, bn_dw_v, ydhl);
  k_pw_mfma<<<dim3(256, 2), 256, 0, stream>>>(ydhl, wpw_hi, wpw_lo, bn_pw_g, bn_pw_b,
                                              bn_pw_m, bn_pw_v, (float*)d_out);
}